// Round 3
// baseline (3055.844 us; speedup 1.0000x reference)
//
#include <hip/hip_runtime.h>

#define NG 1024
#define SCAN_B 1024
#define BSH 6                    // 64 nodes per bucket
#define BNODES 64

// ---------------- zero: degi, bucket cursors, pooled, cnt -------------------
__global__ void k_zero(int* __restrict__ degi, int* __restrict__ bcur,
                       float* __restrict__ pooled, float* __restrict__ cnt,
                       int N, int NBK) {
    int i = blockIdx.x * blockDim.x + threadIdx.x;
    if (i < N) degi[i] = 0;
    if (i < NBK) bcur[i] = 0;
    if (i < NG * 32) pooled[i] = 0.0f;
    if (i < NG) cnt[i] = 0.0f;
}

// ---------------- degree histogram over dst (int atomics) -------------------
__global__ void k_deg(const int* __restrict__ dst, int* __restrict__ degi, int E) {
    int e = blockIdx.x * blockDim.x + threadIdx.x;
    if (e < E) atomicAdd(&degi[dst[e]], 1);
}

// ---------------- scan stage A: per-block inclusive scan --------------------
__global__ void k_scanA(const int* __restrict__ degi, int* __restrict__ tmp,
                        int* __restrict__ part, int N) {
    __shared__ int s[SCAN_B];
    int gid = blockIdx.x * SCAN_B + threadIdx.x;
    s[threadIdx.x] = (gid < N) ? degi[gid] : 0;
    __syncthreads();
    for (int off = 1; off < SCAN_B; off <<= 1) {
        int t = (threadIdx.x >= off) ? s[threadIdx.x - off] : 0;
        __syncthreads();
        s[threadIdx.x] += t;
        __syncthreads();
    }
    if (gid < N) tmp[gid] = s[threadIdx.x];
    if (threadIdx.x == SCAN_B - 1) part[blockIdx.x] = s[SCAN_B - 1];
}

// ---------------- scan stage B: scan of block partials (single block) -------
__global__ void k_scanB(int* __restrict__ part, int NB) {
    __shared__ int s[SCAN_B];
    int v = (threadIdx.x < NB) ? part[threadIdx.x] : 0;
    s[threadIdx.x] = v;
    __syncthreads();
    for (int off = 1; off < SCAN_B; off <<= 1) {
        int t = (threadIdx.x >= off) ? s[threadIdx.x - off] : 0;
        __syncthreads();
        s[threadIdx.x] += t;
        __syncthreads();
    }
    if (threadIdx.x < NB) part[threadIdx.x] = threadIdx.x ? s[threadIdx.x - 1] : 0;
}

// ------- scan stage C: row_ptr = exclusive scan; dinv -----------------------
__global__ void k_scanC(const int* __restrict__ tmp, const int* __restrict__ part,
                        int* __restrict__ row_ptr, const int* __restrict__ degi,
                        float* __restrict__ dinv, int N) {
    int i = blockIdx.x * blockDim.x + threadIdx.x;
    if (i >= N) return;
    row_ptr[i + 1] = tmp[i] + part[i >> 10];   // SCAN_B = 1024
    if (i == 0) row_ptr[0] = 0;
    dinv[i] = rsqrtf((float)degi[i] + 1.0f);   // +1 self-loop
}

// ------- binning: pack (src, dst&63) into u32, scatter into bucket region ---
__global__ void k_bin(const int* __restrict__ src, const int* __restrict__ dst,
                      const int* __restrict__ row_ptr, int* __restrict__ bcur,
                      unsigned* __restrict__ binned, int E) {
    int e = blockIdx.x * blockDim.x + threadIdx.x;
    if (e >= E) return;
    int d = dst[e];
    int b = d >> BSH;
    int pos = atomicAdd(&bcur[b], 1);
    int base = row_ptr[b << BSH];
    binned[base + pos] = (unsigned)src[e] | ((unsigned)(d & (BNODES - 1)) << 26);
}

// ---------------- layer-1 node transform: hs1 = dinv * (x @ W1) -------------
__global__ void k_l1node(const float* __restrict__ x, const float* __restrict__ W1,
                         const float* __restrict__ dinv, float* __restrict__ hs1, int N) {
    __shared__ float sW[48];
    if (threadIdx.x < 48) sW[threadIdx.x] = W1[threadIdx.x];
    __syncthreads();
    int v = blockIdx.x * blockDim.x + threadIdx.x;
    if (v >= N) return;
    float x0 = x[v * 3 + 0], x1 = x[v * 3 + 1], x2 = x[v * 3 + 2];
    float d = dinv[v];
#pragma unroll
    for (int f = 0; f < 16; ++f)
        hs1[v * 16 + f] = d * (x0 * sW[f] + x1 * sW[16 + f] + x2 * sW[32 + f]);
}

// ------- bucket aggregate layer 1: LDS acc, 4 lanes/edge (F=16) -------------
__global__ __launch_bounds__(256) void k_bucket16(
        const unsigned* __restrict__ binned, const int* __restrict__ row_ptr,
        const float* __restrict__ hs1, const float* __restrict__ dinv,
        const float* __restrict__ b1, float* __restrict__ h1, int N) {
    __shared__ float acc[BNODES * 17];
    int t = threadIdx.x;
    for (int i = t; i < BNODES * 17; i += 256) acc[i] = 0.0f;
    __syncthreads();
    int first = blockIdx.x << BSH;
    int nxt = first + BNODES; if (nxt > N) nxt = N;
    int beg = row_ptr[first], end = row_ptr[nxt];
    const float4* hs4 = (const float4*)hs1;
    int q = t & 3;
    for (int e = beg + (t >> 2); e < end; e += 64) {
        unsigned ed = binned[e];
        int s  = (int)(ed & 0x3FFFFFFu);
        int dl = (int)(ed >> 26);
        float4 a = hs4[s * 4 + q];
        float* p = &acc[dl * 17 + q * 4];
        atomicAdd(p + 0, a.x); atomicAdd(p + 1, a.y);
        atomicAdd(p + 2, a.z); atomicAdd(p + 3, a.w);
    }
    __syncthreads();
    int v = t >> 2, gv = first + v;
    if (gv < N) {
        float4 self = hs4[gv * 4 + q];
        const float* p = &acc[v * 17 + q * 4];
        float d = dinv[gv];
        float4 bb = ((const float4*)b1)[q];
        float4 h;
        h.x = fmaxf(d * (self.x + p[0]) + bb.x, 0.0f);
        h.y = fmaxf(d * (self.y + p[1]) + bb.y, 0.0f);
        h.z = fmaxf(d * (self.z + p[2]) + bb.z, 0.0f);
        h.w = fmaxf(d * (self.w + p[3]) + bb.w, 0.0f);
        ((float4*)h1)[gv * 4 + q] = h;
    }
}

// ------- layer-2 node transform: hs2 = dinv * (h1 @ W2) ---------------------
__global__ void k_mid2(const float* __restrict__ h1, const float* __restrict__ W2,
                       const float* __restrict__ dinv, float* __restrict__ hs2, int N) {
    __shared__ float sW[16 * 32];
    for (int i = threadIdx.x; i < 512; i += blockDim.x) sW[i] = W2[i];
    __syncthreads();
    int v = blockIdx.x * blockDim.x + threadIdx.x;
    if (v >= N) return;
    float d = dinv[v];
    float a[16];
#pragma unroll
    for (int k = 0; k < 16; ++k) a[k] = h1[v * 16 + k];
#pragma unroll
    for (int f = 0; f < 32; ++f) {
        float s = 0.0f;
#pragma unroll
        for (int k = 0; k < 16; ++k) s += a[k] * sW[k * 32 + f];
        hs2[v * 32 + f] = d * s;
    }
}

// ------- bucket aggregate layer 2 + fused mean-pool (F=32) ------------------
__global__ __launch_bounds__(256) void k_bucket32(
        const unsigned* __restrict__ binned, const int* __restrict__ row_ptr,
        const float* __restrict__ hs2, const float* __restrict__ dinv,
        const float* __restrict__ b2, const int* __restrict__ batch,
        float* __restrict__ pooled, float* __restrict__ cnt, int N) {
    __shared__ float acc[BNODES * 33];
    int t = threadIdx.x;
    for (int i = t; i < BNODES * 33; i += 256) acc[i] = 0.0f;
    __syncthreads();
    int first = blockIdx.x << BSH;
    int nxt = first + BNODES; if (nxt > N) nxt = N;
    int beg = row_ptr[first], end = row_ptr[nxt];
    const float4* hs4 = (const float4*)hs2;
    {
        int q = t & 7;
        for (int e = beg + (t >> 3); e < end; e += 32) {
            unsigned ed = binned[e];
            int s  = (int)(ed & 0x3FFFFFFu);
            int dl = (int)(ed >> 26);
            float4 a = hs4[s * 8 + q];
            float* p = &acc[dl * 33 + q * 4];
            atomicAdd(p + 0, a.x); atomicAdd(p + 1, a.y);
            atomicAdd(p + 2, a.z); atomicAdd(p + 3, a.w);
        }
    }
    __syncthreads();
    int v = t >> 2, gv = first + v;
    if (gv < N) {
        float d = dinv[gv];
        int g = batch[gv];
#pragma unroll
        for (int jj = 0; jj < 2; ++jj) {
            int j = (t & 3) + jj * 4;
            float4 self = hs4[gv * 8 + j];
            const float* p = &acc[v * 33 + j * 4];
            float4 bb = ((const float4*)b2)[j];
            float h0 = fmaxf(d * (self.x + p[0]) + bb.x, 0.0f);
            float h1v = fmaxf(d * (self.y + p[1]) + bb.y, 0.0f);
            float h2v = fmaxf(d * (self.z + p[2]) + bb.z, 0.0f);
            float h3 = fmaxf(d * (self.w + p[3]) + bb.w, 0.0f);
            float* pp = &pooled[g * 32 + j * 4];
            atomicAdd(pp + 0, h0); atomicAdd(pp + 1, h1v);
            atomicAdd(pp + 2, h2v); atomicAdd(pp + 3, h3);
        }
        if ((t & 3) == 0) atomicAdd(&cnt[g], 1.0f);
    }
}

// ------- final linear head: out[g] = (pooled[g]/cnt[g]) @ Wl + bl -----------
__global__ void k_out(const float* __restrict__ pooled, const float* __restrict__ cnt,
                      const float* __restrict__ Wl, const float* __restrict__ bl,
                      float* __restrict__ out) {
    int t = blockIdx.x * blockDim.x + threadIdx.x;
    if (t >= NG * 3) return;
    int g = t / 3, c = t % 3;
    float inv = 1.0f / fmaxf(cnt[g], 1.0f);
    float s = bl[c];
#pragma unroll
    for (int f = 0; f < 32; ++f) s += pooled[g * 32 + f] * inv * Wl[f * 3 + c];
    out[g * 3 + c] = s;
}

extern "C" void kernel_launch(void* const* d_in, const int* in_sizes, int n_in,
                              void* d_out, int out_size, void* d_ws, size_t ws_size,
                              hipStream_t stream) {
    const float* x     = (const float*)d_in[0];
    const int*   ei    = (const int*)d_in[1];
    const int*   batch = (const int*)d_in[2];
    const float* W1    = (const float*)d_in[3];
    const float* b1    = (const float*)d_in[4];
    const float* W2    = (const float*)d_in[5];
    const float* b2    = (const float*)d_in[6];
    const float* Wl    = (const float*)d_in[7];
    const float* bl    = (const float*)d_in[8];

    const int N = in_sizes[0] / 3;
    const int E = in_sizes[1] / 2;
    const int* src = ei;
    const int* dst = ei + E;
    const int NBK = (N + BNODES - 1) >> BSH;

    char* w = (char*)d_ws;
    int*      degi    = (int*)w;      w += (size_t)N * 4;
    int*      row_ptr = (int*)w;      w += (size_t)(N + 1) * 4;
    int*      part    = (int*)w;      w += (size_t)SCAN_B * 4;
    int*      tmp     = (int*)w;      w += (size_t)N * 4;
    float*    dinv    = (float*)w;    w += (size_t)N * 4;
    int*      bcur    = (int*)w;      w += (size_t)NBK * 4;
    unsigned* binned  = (unsigned*)w; w += (size_t)E * 4;
    float*    hs1     = (float*)w;    w += (size_t)N * 16 * 4;
    float*    h1      = (float*)w;    w += (size_t)N * 16 * 4;
    float*    hs2     = (float*)w;    w += (size_t)N * 32 * 4;
    float*    pooled  = (float*)w;    w += (size_t)NG * 32 * 4;
    float*    cnt     = (float*)w;    w += (size_t)NG * 4;

    const int B = 256;
    const int gN = (N + B - 1) / B;
    const int gE = (E + B - 1) / B;
    const int NB = (N + SCAN_B - 1) / SCAN_B;

    k_zero<<<gN, B, 0, stream>>>(degi, bcur, pooled, cnt, N, NBK);
    k_deg<<<gE, B, 0, stream>>>(dst, degi, E);
    k_scanA<<<NB, SCAN_B, 0, stream>>>(degi, tmp, part, N);
    k_scanB<<<1, SCAN_B, 0, stream>>>(part, NB);
    k_scanC<<<gN, B, 0, stream>>>(tmp, part, row_ptr, degi, dinv, N);
    k_bin<<<gE, B, 0, stream>>>(src, dst, row_ptr, bcur, binned, E);
    k_l1node<<<gN, B, 0, stream>>>(x, W1, dinv, hs1, N);
    k_bucket16<<<NBK, B, 0, stream>>>(binned, row_ptr, hs1, dinv, b1, h1, N);
    k_mid2<<<gN, B, 0, stream>>>(h1, W2, dinv, hs2, N);
    k_bucket32<<<NBK, B, 0, stream>>>(binned, row_ptr, hs2, dinv, b2, batch,
                                      pooled, cnt, N);
    k_out<<<(NG * 3 + B - 1) / B, B, 0, stream>>>(pooled, cnt, Wl, bl, (float*)d_out);
}

// Round 4
// 1721.381 us; speedup vs baseline: 1.7752x; 1.7752x over previous
//
#include <hip/hip_runtime.h>

#define NG 1024
#define SCAN_B 1024
#define BSH 6                    // 64 nodes per bucket
#define BNODES 64

// ---------------- zero: degi, bucket cursors, pooled, cnt -------------------
__global__ void k_zero(int* __restrict__ degi, int* __restrict__ bcur,
                       float* __restrict__ pooled, float* __restrict__ cnt,
                       int N, int NBK) {
    int i = blockIdx.x * blockDim.x + threadIdx.x;
    if (i < N) degi[i] = 0;
    if (i < NBK) bcur[i] = 0;
    if (i < NG * 32) pooled[i] = 0.0f;
    if (i < NG) cnt[i] = 0.0f;
}

// ---------------- degree histogram over dst (int atomics) -------------------
__global__ void k_deg(const int* __restrict__ dst, int* __restrict__ degi, int E) {
    int e = blockIdx.x * blockDim.x + threadIdx.x;
    if (e < E) atomicAdd(&degi[dst[e]], 1);
}

// ---------------- scan stage A: per-block inclusive scan --------------------
__global__ void k_scanA(const int* __restrict__ degi, int* __restrict__ tmp,
                        int* __restrict__ part, int N) {
    __shared__ int s[SCAN_B];
    int gid = blockIdx.x * SCAN_B + threadIdx.x;
    s[threadIdx.x] = (gid < N) ? degi[gid] : 0;
    __syncthreads();
    for (int off = 1; off < SCAN_B; off <<= 1) {
        int t = (threadIdx.x >= off) ? s[threadIdx.x - off] : 0;
        __syncthreads();
        s[threadIdx.x] += t;
        __syncthreads();
    }
    if (gid < N) tmp[gid] = s[threadIdx.x];
    if (threadIdx.x == SCAN_B - 1) part[blockIdx.x] = s[SCAN_B - 1];
}

// ---------------- scan stage B: scan of block partials (single block) -------
__global__ void k_scanB(int* __restrict__ part, int NB) {
    __shared__ int s[SCAN_B];
    int v = (threadIdx.x < NB) ? part[threadIdx.x] : 0;
    s[threadIdx.x] = v;
    __syncthreads();
    for (int off = 1; off < SCAN_B; off <<= 1) {
        int t = (threadIdx.x >= off) ? s[threadIdx.x - off] : 0;
        __syncthreads();
        s[threadIdx.x] += t;
        __syncthreads();
    }
    if (threadIdx.x < NB) part[threadIdx.x] = threadIdx.x ? s[threadIdx.x - 1] : 0;
}

// ------- scan stage C: row_ptr = exclusive scan; dinv -----------------------
__global__ void k_scanC(const int* __restrict__ tmp, const int* __restrict__ part,
                        int* __restrict__ row_ptr, const int* __restrict__ degi,
                        float* __restrict__ dinv, int N) {
    int i = blockIdx.x * blockDim.x + threadIdx.x;
    if (i >= N) return;
    row_ptr[i + 1] = tmp[i] + part[i >> 10];   // SCAN_B = 1024
    if (i == 0) row_ptr[0] = 0;
    dinv[i] = rsqrtf((float)degi[i] + 1.0f);   // +1 self-loop
}

// ------- binning: pack (src, dst&63) into u32, scatter into bucket region ---
__global__ void k_bin(const int* __restrict__ src, const int* __restrict__ dst,
                      const int* __restrict__ row_ptr, int* __restrict__ bcur,
                      unsigned* __restrict__ binned, int E) {
    int e = blockIdx.x * blockDim.x + threadIdx.x;
    if (e >= E) return;
    int d = dst[e];
    int b = d >> BSH;
    int pos = atomicAdd(&bcur[b], 1);
    int base = row_ptr[b << BSH];
    binned[base + pos] = (unsigned)src[e] | ((unsigned)(d & (BNODES - 1)) << 26);
}

// ------- per-bucket counting sort: binned -> per-node CSR -------------------
__global__ __launch_bounds__(256) void k_csr(
        const unsigned* __restrict__ binned, const int* __restrict__ row_ptr,
        int* __restrict__ csr, int N) {
    __shared__ int cur[BNODES];
    __shared__ int rp[BNODES];
    int t = threadIdx.x;
    int first = blockIdx.x << BSH;
    if (t < BNODES) {
        cur[t] = 0;
        int gv = first + t;
        rp[t] = (gv < N) ? row_ptr[gv] : 0;
    }
    __syncthreads();
    int nxt = first + BNODES; if (nxt > N) nxt = N;
    int beg = row_ptr[first], end = row_ptr[nxt];
    for (int e = beg + t; e < end; e += 256) {
        unsigned ed = binned[e];
        int s  = (int)(ed & 0x3FFFFFFu);
        int dl = (int)(ed >> 26);
        int pos = atomicAdd(&cur[dl], 1);
        csr[rp[dl] + pos] = s;
    }
}

// ---------------- layer-1 node transform: hs1 = dinv * (x @ W1) -------------
__global__ void k_l1node(const float* __restrict__ x, const float* __restrict__ W1,
                         const float* __restrict__ dinv, float* __restrict__ hs1, int N) {
    __shared__ float sW[48];
    if (threadIdx.x < 48) sW[threadIdx.x] = W1[threadIdx.x];
    __syncthreads();
    int v = blockIdx.x * blockDim.x + threadIdx.x;
    if (v >= N) return;
    float x0 = x[v * 3 + 0], x1 = x[v * 3 + 1], x2 = x[v * 3 + 2];
    float d = dinv[v];
#pragma unroll
    for (int f = 0; f < 16; ++f)
        hs1[v * 16 + f] = d * (x0 * sW[f] + x1 * sW[16 + f] + x2 * sW[32 + f]);
}

// ------- gather layer 1: h1 = relu(dinv * (self + sum_in hs1[src]) + b1) ----
// 4 lanes per node, float4 each (F=16)
__global__ void k_gather16(const int* __restrict__ row_ptr, const int* __restrict__ csr,
                           const float* __restrict__ hs1, const float* __restrict__ dinv,
                           const float* __restrict__ b1, float* __restrict__ h1, int N) {
    int t = blockIdx.x * blockDim.x + threadIdx.x;
    int v = t >> 2, q = t & 3;
    if (v >= N) return;
    const float4* hs4 = (const float4*)hs1;
    float4 sum = hs4[v * 4 + q];               // self-loop
    int beg = row_ptr[v], end = row_ptr[v + 1];
    for (int i = beg; i < end; ++i) {
        int s = csr[i];
        float4 a = hs4[s * 4 + q];
        sum.x += a.x; sum.y += a.y; sum.z += a.z; sum.w += a.w;
    }
    float d = dinv[v];
    float4 b = ((const float4*)b1)[q];
    float4 h;
    h.x = fmaxf(d * sum.x + b.x, 0.0f);
    h.y = fmaxf(d * sum.y + b.y, 0.0f);
    h.z = fmaxf(d * sum.z + b.z, 0.0f);
    h.w = fmaxf(d * sum.w + b.w, 0.0f);
    ((float4*)h1)[v * 4 + q] = h;
}

// ------- layer-2 node transform: hs2 = dinv * (h1 @ W2) ---------------------
__global__ void k_mid2(const float* __restrict__ h1, const float* __restrict__ W2,
                       const float* __restrict__ dinv, float* __restrict__ hs2, int N) {
    __shared__ float sW[16 * 32];
    for (int i = threadIdx.x; i < 512; i += blockDim.x) sW[i] = W2[i];
    __syncthreads();
    int v = blockIdx.x * blockDim.x + threadIdx.x;
    if (v >= N) return;
    float d = dinv[v];
    float a[16];
#pragma unroll
    for (int k = 0; k < 16; ++k) a[k] = h1[v * 16 + k];
#pragma unroll
    for (int f = 0; f < 32; ++f) {
        float s = 0.0f;
#pragma unroll
        for (int k = 0; k < 16; ++k) s += a[k] * sW[k * 32 + f];
        hs2[v * 32 + f] = d * s;
    }
}

// ------- gather layer 2 + fused mean-pool accumulation ----------------------
// 8 lanes per node, float4 each (F=32)
__global__ void k_gather32(const int* __restrict__ row_ptr, const int* __restrict__ csr,
                           const float* __restrict__ hs2, const float* __restrict__ dinv,
                           const float* __restrict__ b2, const int* __restrict__ batch,
                           float* __restrict__ pooled, float* __restrict__ cnt, int N) {
    int t = blockIdx.x * blockDim.x + threadIdx.x;
    int v = t >> 3, q = t & 7;
    if (v >= N) return;
    const float4* hs4 = (const float4*)hs2;
    float4 sum = hs4[v * 8 + q];               // self-loop
    int beg = row_ptr[v], end = row_ptr[v + 1];
    for (int i = beg; i < end; ++i) {
        int s = csr[i];
        float4 a = hs4[s * 8 + q];
        sum.x += a.x; sum.y += a.y; sum.z += a.z; sum.w += a.w;
    }
    float d = dinv[v];
    float4 b = ((const float4*)b2)[q];
    float4 h;
    h.x = fmaxf(d * sum.x + b.x, 0.0f);
    h.y = fmaxf(d * sum.y + b.y, 0.0f);
    h.z = fmaxf(d * sum.z + b.z, 0.0f);
    h.w = fmaxf(d * sum.w + b.w, 0.0f);
    int g = batch[v];
    float* p = &pooled[g * 32 + q * 4];
    atomicAdd(p + 0, h.x);
    atomicAdd(p + 1, h.y);
    atomicAdd(p + 2, h.z);
    atomicAdd(p + 3, h.w);
    if (q == 0) atomicAdd(&cnt[g], 1.0f);
}

// ------- final linear head: out[g] = (pooled[g]/cnt[g]) @ Wl + bl -----------
__global__ void k_out(const float* __restrict__ pooled, const float* __restrict__ cnt,
                      const float* __restrict__ Wl, const float* __restrict__ bl,
                      float* __restrict__ out) {
    int t = blockIdx.x * blockDim.x + threadIdx.x;
    if (t >= NG * 3) return;
    int g = t / 3, c = t % 3;
    float inv = 1.0f / fmaxf(cnt[g], 1.0f);
    float s = bl[c];
#pragma unroll
    for (int f = 0; f < 32; ++f) s += pooled[g * 32 + f] * inv * Wl[f * 3 + c];
    out[g * 3 + c] = s;
}

extern "C" void kernel_launch(void* const* d_in, const int* in_sizes, int n_in,
                              void* d_out, int out_size, void* d_ws, size_t ws_size,
                              hipStream_t stream) {
    const float* x     = (const float*)d_in[0];
    const int*   ei    = (const int*)d_in[1];
    const int*   batch = (const int*)d_in[2];
    const float* W1    = (const float*)d_in[3];
    const float* b1    = (const float*)d_in[4];
    const float* W2    = (const float*)d_in[5];
    const float* b2    = (const float*)d_in[6];
    const float* Wl    = (const float*)d_in[7];
    const float* bl    = (const float*)d_in[8];

    const int N = in_sizes[0] / 3;
    const int E = in_sizes[1] / 2;
    const int* src = ei;
    const int* dst = ei + E;
    const int NBK = (N + BNODES - 1) >> BSH;

    char* w = (char*)d_ws;
    int*      degi    = (int*)w;      w += (size_t)N * 4;
    int*      row_ptr = (int*)w;      w += (size_t)(N + 1) * 4;
    int*      part    = (int*)w;      w += (size_t)SCAN_B * 4;
    int*      tmp     = (int*)w;      w += (size_t)N * 4;
    float*    dinv    = (float*)w;    w += (size_t)N * 4;
    int*      bcur    = (int*)w;      w += (size_t)NBK * 4;
    int*      csr     = (int*)w;      w += (size_t)E * 4;
    // feature region overlaid with the transient binned array:
    // binned (E u32, dead after k_csr) aliases {hs1,h1,hs2} (N*64 floats),
    // which are first written only after k_csr completes.
    char*     fb      = w;
    unsigned* binned  = (unsigned*)fb;
    float*    hs1     = (float*)fb;                               // N*16
    float*    h1      = (float*)(fb + (size_t)N * 16 * 4);        // N*16
    float*    hs2     = (float*)(fb + (size_t)N * 32 * 4);        // N*32
    w = fb + (size_t)N * 64 * 4;
    float*    pooled  = (float*)w;    w += (size_t)NG * 32 * 4;
    float*    cnt     = (float*)w;    w += (size_t)NG * 4;

    const int B = 256;
    const int gN = (N + B - 1) / B;
    const int gE = (E + B - 1) / B;
    const int NB = (N + SCAN_B - 1) / SCAN_B;

    k_zero<<<gN, B, 0, stream>>>(degi, bcur, pooled, cnt, N, NBK);
    k_deg<<<gE, B, 0, stream>>>(dst, degi, E);
    k_scanA<<<NB, SCAN_B, 0, stream>>>(degi, tmp, part, N);
    k_scanB<<<1, SCAN_B, 0, stream>>>(part, NB);
    k_scanC<<<gN, B, 0, stream>>>(tmp, part, row_ptr, degi, dinv, N);
    k_bin<<<gE, B, 0, stream>>>(src, dst, row_ptr, bcur, binned, E);
    k_csr<<<NBK, B, 0, stream>>>(binned, row_ptr, csr, N);
    k_l1node<<<gN, B, 0, stream>>>(x, W1, dinv, hs1, N);
    k_gather16<<<(N * 4 + B - 1) / B, B, 0, stream>>>(row_ptr, csr, hs1, dinv, b1, h1, N);
    k_mid2<<<gN, B, 0, stream>>>(h1, W2, dinv, hs2, N);
    k_gather32<<<(N * 8 + B - 1) / B, B, 0, stream>>>(row_ptr, csr, hs2, dinv, b2, batch,
                                                     pooled, cnt, N);
    k_out<<<(NG * 3 + B - 1) / B, B, 0, stream>>>(pooled, cnt, Wl, bl, (float*)d_out);
}

// Round 6
// 793.879 us; speedup vs baseline: 3.8493x; 2.1683x over previous
//
#include <hip/hip_runtime.h>

#define NG 1024
#define SCAN_B 1024
#define BSH 6                    // 64 nodes per bucket
#define BNODES 64
#define MAXBK 4096               // max buckets (N <= 262144)
#define NB2 256                  // histogram / scatter blocks

// ---------------- zero: degi, pooled, cnt -----------------------------------
__global__ void k_zero(int* __restrict__ degi, float* __restrict__ pooled,
                       float* __restrict__ cnt, int N) {
    int i = blockIdx.x * blockDim.x + threadIdx.x;
    if (i < N) degi[i] = 0;
    if (i < NG * 32) pooled[i] = 0.0f;
    if (i < NG) cnt[i] = 0.0f;
}

// ---------------- degree histogram over dst ---------------------------------
__global__ void k_deg(const int* __restrict__ dst, int* __restrict__ degi, int E) {
    int e = blockIdx.x * blockDim.x + threadIdx.x;
    if (e < E) atomicAdd(&degi[dst[e]], 1);
}

// ---------------- generic scan stage A: per-block inclusive scan ------------
__global__ void k_scanA(const int* __restrict__ in, int* __restrict__ tmp,
                        int* __restrict__ part, int L) {
    __shared__ int s[SCAN_B];
    int gid = blockIdx.x * SCAN_B + threadIdx.x;
    s[threadIdx.x] = (gid < L) ? in[gid] : 0;
    __syncthreads();
    for (int off = 1; off < SCAN_B; off <<= 1) {
        int t = (threadIdx.x >= off) ? s[threadIdx.x - off] : 0;
        __syncthreads();
        s[threadIdx.x] += t;
        __syncthreads();
    }
    if (gid < L) tmp[gid] = s[threadIdx.x];
    if (threadIdx.x == SCAN_B - 1) part[blockIdx.x] = s[SCAN_B - 1];
}

// ---------------- generic scan stage B: exclusive scan of partials ----------
__global__ void k_scanB(int* __restrict__ part, int NB) {
    __shared__ int s[SCAN_B];
    int v = (threadIdx.x < NB) ? part[threadIdx.x] : 0;
    s[threadIdx.x] = v;
    __syncthreads();
    for (int off = 1; off < SCAN_B; off <<= 1) {
        int t = (threadIdx.x >= off) ? s[threadIdx.x - off] : 0;
        __syncthreads();
        s[threadIdx.x] += t;
        __syncthreads();
    }
    if (threadIdx.x < NB) part[threadIdx.x] = threadIdx.x ? s[threadIdx.x - 1] : 0;
}

// ------- node-scan apply: row_ptr = exclusive scan of degi; dinv ------------
__global__ void k_scanC(const int* __restrict__ tmp, const int* __restrict__ part,
                        int* __restrict__ row_ptr, const int* __restrict__ degi,
                        float* __restrict__ dinv, int N) {
    int i = blockIdx.x * blockDim.x + threadIdx.x;
    if (i >= N) return;
    row_ptr[i + 1] = tmp[i] + part[i >> 10];
    if (i == 0) row_ptr[0] = 0;
    dinv[i] = rsqrtf((float)degi[i] + 1.0f);   // +1 self-loop
}

// ------- hist apply: offT = (incl + part) - orig = exclusive, in place ------
__global__ void k_applyT(const int* __restrict__ tmp2, const int* __restrict__ part2,
                         int* __restrict__ histT, int L) {
    int k = blockIdx.x * blockDim.x + threadIdx.x;
    if (k < L) histT[k] = tmp2[k] + part2[k >> 10] - histT[k];
}

// ------- pass 1: per-block bucket histogram (bucket-major output) -----------
__global__ __launch_bounds__(256) void k_hist(const int* __restrict__ dst,
                                              int* __restrict__ histT,
                                              int E, int CH, int NBK) {
    __shared__ int cnt_s[MAXBK];
    for (int i = threadIdx.x; i < NBK; i += 256) cnt_s[i] = 0;
    __syncthreads();
    int blk = blockIdx.x;
    int s0 = blk * CH, s1 = s0 + CH; if (s1 > E) s1 = E;
    for (int e = s0 + threadIdx.x; e < s1; e += 256)
        atomicAdd(&cnt_s[dst[e] >> BSH], 1);
    __syncthreads();
    for (int b = threadIdx.x; b < NBK; b += 256)
        histT[b * NB2 + blk] = cnt_s[b];
}

// ------- pass 2: scatter into per-block private windows (no global atomics) -
__global__ __launch_bounds__(256) void k_scatter(const int* __restrict__ src,
                                                 const int* __restrict__ dst,
                                                 const int* __restrict__ offT,
                                                 unsigned* __restrict__ binned,
                                                 int E, int CH, int NBK) {
    __shared__ int cur[MAXBK];
    int blk = blockIdx.x;
    for (int b = threadIdx.x; b < NBK; b += 256) cur[b] = offT[b * NB2 + blk];
    __syncthreads();
    int s0 = blk * CH, s1 = s0 + CH; if (s1 > E) s1 = E;
    for (int e = s0 + threadIdx.x; e < s1; e += 256) {
        int d = dst[e];
        int b = d >> BSH;
        int pos = atomicAdd(&cur[b], 1);       // LDS atomic, block-private
        binned[pos] = (unsigned)src[e] | ((unsigned)(d & (BNODES - 1)) << 26);
    }
}

// ------- per-bucket counting sort: binned -> per-node CSR -------------------
__global__ __launch_bounds__(256) void k_csr(
        const unsigned* __restrict__ binned, const int* __restrict__ row_ptr,
        int* __restrict__ csr, int N) {
    __shared__ int cur[BNODES];
    __shared__ int rp[BNODES];
    int t = threadIdx.x;
    int first = blockIdx.x << BSH;
    if (t < BNODES) {
        cur[t] = 0;
        int gv = first + t;
        rp[t] = (gv < N) ? row_ptr[gv] : 0;
    }
    __syncthreads();
    int nxt = first + BNODES; if (nxt > N) nxt = N;
    int beg = row_ptr[first], end = row_ptr[nxt];
    for (int e = beg + t; e < end; e += 256) {
        unsigned ed = binned[e];
        int s  = (int)(ed & 0x3FFFFFFu);
        int dl = (int)(ed >> 26);
        int pos = atomicAdd(&cur[dl], 1);
        csr[rp[dl] + pos] = s;
    }
}

// ------- xd[v] = dinv[v] * x[v]  (padded to float4) -------------------------
__global__ void k_xd(const float* __restrict__ x, const float* __restrict__ dinv,
                     float4* __restrict__ xd, int N) {
    int v = blockIdx.x * blockDim.x + threadIdx.x;
    if (v >= N) return;
    float d = dinv[v];
    xd[v] = make_float4(d * x[v * 3 + 0], d * x[v * 3 + 1], d * x[v * 3 + 2], 0.0f);
}

// ------- layer 1: gather xd, matmul AFTER aggregation; writes g1 = dinv*h1 --
// 2 lanes per node; each lane sums half the edges, then computes 8 features.
__global__ __launch_bounds__(256) void k_ga(const int* __restrict__ row_ptr,
                                            const int* __restrict__ csr,
                                            const float4* __restrict__ xd,
                                            const float* __restrict__ dinv,
                                            const float* __restrict__ W1,
                                            const float* __restrict__ b1,
                                            float* __restrict__ g1, int N) {
    __shared__ float sW[48];
    __shared__ float sb[16];
    if (threadIdx.x < 48) sW[threadIdx.x] = W1[threadIdx.x];
    if (threadIdx.x < 16) sb[threadIdx.x] = b1[threadIdx.x];
    __syncthreads();
    int t = blockIdx.x * blockDim.x + threadIdx.x;
    int v = t >> 1, p = t & 1;
    if (v >= N) return;
    int beg = row_ptr[v], end = row_ptr[v + 1];
    float sx = 0.0f, sy = 0.0f, sz = 0.0f;
    for (int e = beg + p; e < end; e += 2) {
        float4 a = xd[csr[e]];
        sx += a.x; sy += a.y; sz += a.z;
    }
    sx += __shfl_xor(sx, 1, 64);
    sy += __shfl_xor(sy, 1, 64);
    sz += __shfl_xor(sz, 1, 64);
    float4 self = xd[v];
    sx += self.x; sy += self.y; sz += self.z;
    float d = dinv[v];
    int f0 = p * 8;
    float o[8];
#pragma unroll
    for (int j = 0; j < 8; ++j) {
        int f = f0 + j;
        float h = fmaxf(d * (sx * sW[f] + sy * sW[16 + f] + sz * sW[32 + f]) + sb[f], 0.0f);
        o[j] = d * h;                          // g1 = dinv * h1
    }
    float4* g4 = (float4*)g1;
    g4[v * 4 + p * 2 + 0] = make_float4(o[0], o[1], o[2], o[3]);
    g4[v * 4 + p * 2 + 1] = make_float4(o[4], o[5], o[6], o[7]);
}

// ------- layer 2: gather g1, matmul after aggregation, fused mean-pool ------
// 4 lanes per node (feature quads), butterfly-share t16, 8 outputs per lane.
__global__ __launch_bounds__(256) void k_gb(const int* __restrict__ row_ptr,
                                            const int* __restrict__ csr,
                                            const float* __restrict__ g1,
                                            const float* __restrict__ dinv,
                                            const float* __restrict__ W2,
                                            const float* __restrict__ b2,
                                            const int* __restrict__ batch,
                                            float* __restrict__ pooled,
                                            float* __restrict__ cnt, int N) {
    __shared__ float sW[512];
    __shared__ float sb[32];
    for (int i = threadIdx.x; i < 512; i += 256) sW[i] = W2[i];
    if (threadIdx.x < 32) sb[threadIdx.x] = b2[threadIdx.x];
    __syncthreads();
    int t = blockIdx.x * blockDim.x + threadIdx.x;
    int v = t >> 2, q = t & 3;
    if (v >= N) return;
    const float4* g4 = (const float4*)g1;
    float4 s = g4[v * 4 + q];                  // self-loop
    int beg = row_ptr[v], end = row_ptr[v + 1];
    for (int e = beg; e < end; ++e) {
        float4 a = g4[csr[e] * 4 + q];
        s.x += a.x; s.y += a.y; s.z += a.z; s.w += a.w;
    }
    // butterfly-share the 4 quads so every lane holds all 16 values
    float me[4] = {s.x, s.y, s.z, s.w};
    float nb[4];
#pragma unroll
    for (int j = 0; j < 4; ++j) nb[j] = __shfl_xor(me[j], 1, 64);
    float e8[8];
    if (q & 1) {
#pragma unroll
        for (int j = 0; j < 4; ++j) { e8[j] = nb[j]; e8[4 + j] = me[j]; }
    } else {
#pragma unroll
        for (int j = 0; j < 4; ++j) { e8[j] = me[j]; e8[4 + j] = nb[j]; }
    }
    float o8[8];
#pragma unroll
    for (int j = 0; j < 8; ++j) o8[j] = __shfl_xor(e8[j], 2, 64);
    float t16[16];
    if (q & 2) {
#pragma unroll
        for (int j = 0; j < 8; ++j) { t16[j] = o8[j]; t16[8 + j] = e8[j]; }
    } else {
#pragma unroll
        for (int j = 0; j < 8; ++j) { t16[j] = e8[j]; t16[8 + j] = o8[j]; }
    }
    float d = dinv[v];
    int f0 = q * 8;
    int g = batch[v];
    float* pp = &pooled[g * 32];
#pragma unroll
    for (int j = 0; j < 8; ++j) {
        float acc = 0.0f;
#pragma unroll
        for (int k = 0; k < 16; ++k) acc += t16[k] * sW[k * 32 + f0 + j];
        float h = fmaxf(d * acc + sb[f0 + j], 0.0f);
        atomicAdd(&pp[f0 + j], h);
    }
    if (q == 0) atomicAdd(&cnt[g], 1.0f);
}

// ------- final linear head ---------------------------------------------------
__global__ void k_out(const float* __restrict__ pooled, const float* __restrict__ cnt,
                      const float* __restrict__ Wl, const float* __restrict__ bl,
                      float* __restrict__ out) {
    int t = blockIdx.x * blockDim.x + threadIdx.x;
    if (t >= NG * 3) return;
    int g = t / 3, c = t % 3;
    float inv = 1.0f / fmaxf(cnt[g], 1.0f);
    float s = bl[c];
#pragma unroll
    for (int f = 0; f < 32; ++f) s += pooled[g * 32 + f] * inv * Wl[f * 3 + c];
    out[g * 3 + c] = s;
}

extern "C" void kernel_launch(void* const* d_in, const int* in_sizes, int n_in,
                              void* d_out, int out_size, void* d_ws, size_t ws_size,
                              hipStream_t stream) {
    const float* x     = (const float*)d_in[0];
    const int*   ei    = (const int*)d_in[1];
    const int*   batch = (const int*)d_in[2];
    const float* W1    = (const float*)d_in[3];
    const float* b1    = (const float*)d_in[4];
    const float* W2    = (const float*)d_in[5];
    const float* b2    = (const float*)d_in[6];
    const float* Wl    = (const float*)d_in[7];
    const float* bl    = (const float*)d_in[8];

    const int N = in_sizes[0] / 3;
    const int E = in_sizes[1] / 2;
    const int* src = ei;
    const int* dst = ei + E;
    const int NBK = (N + BNODES - 1) >> BSH;      // buckets
    const int CH  = (E + NB2 - 1) / NB2;          // edges per hist/scatter block
    const int L   = NBK * NB2;                    // histogram length

    char* w = (char*)d_ws;
    int*      degi    = (int*)w;      w += (size_t)N * 4;
    int*      row_ptr = (int*)w;      w += (size_t)(N + 1) * 4;
    int*      part    = (int*)w;      w += (size_t)SCAN_B * 4;
    int*      tmp     = (int*)w;      w += (size_t)N * 4;
    float*    dinv    = (float*)w;    w += (size_t)N * 4;
    int*      histT   = (int*)w;      w += (size_t)L * 4;
    int*      tmp2    = (int*)w;      w += (size_t)L * 4;
    int*      part2   = (int*)w;      w += (size_t)SCAN_B * 4;
    int*      csr     = (int*)w;      w += (size_t)E * 4;
    // transient binned (E u32) aliases the feature buffers (xd: N float4,
    // g1: N*16 floats), which are written only after k_csr consumed binned.
    char*     fb      = w;
    unsigned* binned  = (unsigned*)fb;
    float4*   xd      = (float4*)fb;                            // N float4
    float*    g1      = (float*)(fb + (size_t)N * 16);          // N*16 floats
    size_t fbsz = (size_t)E * 4;
    size_t featsz = (size_t)N * 16 + (size_t)N * 64;
    w = fb + (fbsz > featsz ? fbsz : featsz);
    float*    pooled  = (float*)w;    w += (size_t)NG * 32 * 4;
    float*    cnt     = (float*)w;    w += (size_t)NG * 4;

    const int B = 256;
    const int gN  = (N + B - 1) / B;
    const int gE  = (E + B - 1) / B;
    const int NBn = (N + SCAN_B - 1) / SCAN_B;    // node-scan blocks
    const int NBl = (L + SCAN_B - 1) / SCAN_B;    // hist-scan blocks

    k_zero<<<gN, B, 0, stream>>>(degi, pooled, cnt, N);
    k_deg<<<gE, B, 0, stream>>>(dst, degi, E);
    k_scanA<<<NBn, SCAN_B, 0, stream>>>(degi, tmp, part, N);
    k_scanB<<<1, SCAN_B, 0, stream>>>(part, NBn);
    k_scanC<<<gN, B, 0, stream>>>(tmp, part, row_ptr, degi, dinv, N);

    k_hist<<<NB2, B, 0, stream>>>(dst, histT, E, CH, NBK);
    k_scanA<<<NBl, SCAN_B, 0, stream>>>(histT, tmp2, part2, L);
    k_scanB<<<1, SCAN_B, 0, stream>>>(part2, NBl);
    k_applyT<<<(L + B - 1) / B, B, 0, stream>>>(tmp2, part2, histT, L);
    k_scatter<<<NB2, B, 0, stream>>>(src, dst, histT, binned, E, CH, NBK);
    k_csr<<<NBK, B, 0, stream>>>(binned, row_ptr, csr, N);

    k_xd<<<gN, B, 0, stream>>>(x, dinv, xd, N);
    k_ga<<<(N * 2 + B - 1) / B, B, 0, stream>>>(row_ptr, csr, xd, dinv, W1, b1, g1, N);
    k_gb<<<(N * 4 + B - 1) / B, B, 0, stream>>>(row_ptr, csr, g1, dinv, W2, b2, batch,
                                                pooled, cnt, N);
    k_out<<<(NG * 3 + B - 1) / B, B, 0, stream>>>(pooled, cnt, Wl, bl, (float*)d_out);
}

// Round 7
// 664.211 us; speedup vs baseline: 4.6007x; 1.1952x over previous
//
#include <hip/hip_runtime.h>
#include <hip/hip_fp16.h>

#define NG 1024
#define SCAN_B 1024
#define BSH 6                    // 64 nodes per bucket
#define BNODES 64
#define MAXBK 4096               // max buckets (N <= 262144)
#define NB2 256                  // histogram / scatter blocks

// ---------------- zero: degi, pooled, cnt -----------------------------------
__global__ void k_zero(int* __restrict__ degi, float* __restrict__ pooled,
                       float* __restrict__ cnt, int N) {
    int i = blockIdx.x * blockDim.x + threadIdx.x;
    if (i < N) degi[i] = 0;
    if (i < NG * 32) pooled[i] = 0.0f;
    if (i < NG) cnt[i] = 0.0f;
}

// ---------------- degree histogram over dst ---------------------------------
__global__ void k_deg(const int* __restrict__ dst, int* __restrict__ degi, int E) {
    int e = blockIdx.x * blockDim.x + threadIdx.x;
    if (e < E) atomicAdd(&degi[dst[e]], 1);
}

// ---------------- generic scan stage A: per-block inclusive scan ------------
__global__ void k_scanA(const int* __restrict__ in, int* __restrict__ tmp,
                        int* __restrict__ part, int L) {
    __shared__ int s[SCAN_B];
    int gid = blockIdx.x * SCAN_B + threadIdx.x;
    s[threadIdx.x] = (gid < L) ? in[gid] : 0;
    __syncthreads();
    for (int off = 1; off < SCAN_B; off <<= 1) {
        int t = (threadIdx.x >= off) ? s[threadIdx.x - off] : 0;
        __syncthreads();
        s[threadIdx.x] += t;
        __syncthreads();
    }
    if (gid < L) tmp[gid] = s[threadIdx.x];
    if (threadIdx.x == SCAN_B - 1) part[blockIdx.x] = s[SCAN_B - 1];
}

// ---------------- generic scan stage B: exclusive scan of partials ----------
__global__ void k_scanB(int* __restrict__ part, int NB) {
    __shared__ int s[SCAN_B];
    int v = (threadIdx.x < NB) ? part[threadIdx.x] : 0;
    s[threadIdx.x] = v;
    __syncthreads();
    for (int off = 1; off < SCAN_B; off <<= 1) {
        int t = (threadIdx.x >= off) ? s[threadIdx.x - off] : 0;
        __syncthreads();
        s[threadIdx.x] += t;
        __syncthreads();
    }
    if (threadIdx.x < NB) part[threadIdx.x] = threadIdx.x ? s[threadIdx.x - 1] : 0;
}

// ------- node-scan apply: row_ptr = exclusive scan of degi; dinv ------------
__global__ void k_scanC(const int* __restrict__ tmp, const int* __restrict__ part,
                        int* __restrict__ row_ptr, const int* __restrict__ degi,
                        float* __restrict__ dinv, int N) {
    int i = blockIdx.x * blockDim.x + threadIdx.x;
    if (i >= N) return;
    row_ptr[i + 1] = tmp[i] + part[i >> 10];
    if (i == 0) row_ptr[0] = 0;
    dinv[i] = rsqrtf((float)degi[i] + 1.0f);   // +1 self-loop
}

// ------- hist apply: offT = (incl + part) - orig = exclusive, in place ------
__global__ void k_applyT(const int* __restrict__ tmp2, const int* __restrict__ part2,
                         int* __restrict__ histT, int L) {
    int k = blockIdx.x * blockDim.x + threadIdx.x;
    if (k < L) histT[k] = tmp2[k] + part2[k >> 10] - histT[k];
}

// ------- pass 1: per-block bucket histogram (bucket-major output) -----------
__global__ __launch_bounds__(256) void k_hist(const int* __restrict__ dst,
                                              int* __restrict__ histT,
                                              int E, int CH, int NBK) {
    __shared__ int cnt_s[MAXBK];
    for (int i = threadIdx.x; i < NBK; i += 256) cnt_s[i] = 0;
    __syncthreads();
    int blk = blockIdx.x;
    int s0 = blk * CH, s1 = s0 + CH; if (s1 > E) s1 = E;
    for (int e = s0 + threadIdx.x; e < s1; e += 256)
        atomicAdd(&cnt_s[dst[e] >> BSH], 1);
    __syncthreads();
    for (int b = threadIdx.x; b < NBK; b += 256)
        histT[b * NB2 + blk] = cnt_s[b];
}

// ------- pass 2: scatter into per-block private windows (no global atomics) -
__global__ __launch_bounds__(256) void k_scatter(const int* __restrict__ src,
                                                 const int* __restrict__ dst,
                                                 const int* __restrict__ offT,
                                                 unsigned* __restrict__ binned,
                                                 int E, int CH, int NBK) {
    __shared__ int cur[MAXBK];
    int blk = blockIdx.x;
    for (int b = threadIdx.x; b < NBK; b += 256) cur[b] = offT[b * NB2 + blk];
    __syncthreads();
    int s0 = blk * CH, s1 = s0 + CH; if (s1 > E) s1 = E;
    for (int e = s0 + threadIdx.x; e < s1; e += 256) {
        int d = dst[e];
        int b = d >> BSH;
        int pos = atomicAdd(&cur[b], 1);       // LDS atomic, block-private
        binned[pos] = (unsigned)src[e] | ((unsigned)(d & (BNODES - 1)) << 26);
    }
}

// ------- per-bucket counting sort: binned -> per-node CSR -------------------
__global__ __launch_bounds__(256) void k_csr(
        const unsigned* __restrict__ binned, const int* __restrict__ row_ptr,
        int* __restrict__ csr, int N) {
    __shared__ int cur[BNODES];
    __shared__ int rp[BNODES];
    int t = threadIdx.x;
    int first = blockIdx.x << BSH;
    if (t < BNODES) {
        cur[t] = 0;
        int gv = first + t;
        rp[t] = (gv < N) ? row_ptr[gv] : 0;
    }
    __syncthreads();
    int nxt = first + BNODES; if (nxt > N) nxt = N;
    int beg = row_ptr[first], end = row_ptr[nxt];
    for (int e = beg + t; e < end; e += 256) {
        unsigned ed = binned[e];
        int s  = (int)(ed & 0x3FFFFFFu);
        int dl = (int)(ed >> 26);
        int pos = atomicAdd(&cur[dl], 1);
        csr[rp[dl] + pos] = s;
    }
}

// ------- xd[v] = dinv[v] * x[v]  (padded to float4, fp32) -------------------
__global__ void k_xd(const float* __restrict__ x, const float* __restrict__ dinv,
                     float4* __restrict__ xd, int N) {
    int v = blockIdx.x * blockDim.x + threadIdx.x;
    if (v >= N) return;
    float d = dinv[v];
    xd[v] = make_float4(d * x[v * 3 + 0], d * x[v * 3 + 1], d * x[v * 3 + 2], 0.0f);
}

// ------- layer 1: gather xd (4-way edge split), matmul after aggregation ----
// writes g1h = fp16(dinv * h1); 4 lanes per node, 4 features per lane.
__global__ __launch_bounds__(256) void k_ga(const int* __restrict__ row_ptr,
                                            const int* __restrict__ csr,
                                            const float4* __restrict__ xd,
                                            const float* __restrict__ dinv,
                                            const float* __restrict__ W1,
                                            const float* __restrict__ b1,
                                            __half* __restrict__ g1h, int N) {
    __shared__ float sW[48];
    __shared__ float sb[16];
    if (threadIdx.x < 48) sW[threadIdx.x] = W1[threadIdx.x];
    if (threadIdx.x < 16) sb[threadIdx.x] = b1[threadIdx.x];
    __syncthreads();
    int t = blockIdx.x * blockDim.x + threadIdx.x;
    int v = t >> 2, l = t & 3;
    if (v >= N) return;
    int beg = row_ptr[v], end = row_ptr[v + 1];
    float sx = 0.0f, sy = 0.0f, sz = 0.0f;
    for (int e = beg + l; e < end; e += 4) {
        float4 a = xd[csr[e]];
        sx += a.x; sy += a.y; sz += a.z;
    }
    sx += __shfl_xor(sx, 1, 64); sy += __shfl_xor(sy, 1, 64); sz += __shfl_xor(sz, 1, 64);
    sx += __shfl_xor(sx, 2, 64); sy += __shfl_xor(sy, 2, 64); sz += __shfl_xor(sz, 2, 64);
    float4 self = xd[v];
    sx += self.x; sy += self.y; sz += self.z;
    float d = dinv[v];
    int f0 = l * 4;
    __half hh[4];
#pragma unroll
    for (int j = 0; j < 4; ++j) {
        int f = f0 + j;
        float h = fmaxf(d * (sx * sW[f] + sy * sW[16 + f] + sz * sW[32 + f]) + sb[f], 0.0f);
        hh[j] = __float2half(d * h);           // g1 = dinv * h1
    }
    __half2 p0 = __halves2half2(hh[0], hh[1]);
    __half2 p1 = __halves2half2(hh[2], hh[3]);
    uint2 u;
    u.x = *(unsigned*)&p0; u.y = *(unsigned*)&p1;
    *(uint2*)(g1h + (size_t)v * 16 + f0) = u;
}

// ------- layer 2: fp16 gather (4-way edge x 2-way feature split), -----------
// matmul after aggregation, fused mean-pool. 8 lanes per node.
__global__ __launch_bounds__(256) void k_gb(const int* __restrict__ row_ptr,
                                            const int* __restrict__ csr,
                                            const __half* __restrict__ g1h,
                                            const float* __restrict__ dinv,
                                            const float* __restrict__ W2,
                                            const float* __restrict__ b2,
                                            const int* __restrict__ batch,
                                            float* __restrict__ pooled,
                                            float* __restrict__ cnt, int N) {
    __shared__ float sW[512];
    __shared__ float sb[32];
    for (int i = threadIdx.x; i < 512; i += 256) sW[i] = W2[i];
    if (threadIdx.x < 32) sb[threadIdx.x] = b2[threadIdx.x];
    __syncthreads();
    int t = blockIdx.x * blockDim.x + threadIdx.x;
    int v = t >> 3, l = t & 7;
    if (v >= N) return;
    int fh = l & 1, ep = l >> 1;
    const char* gbase = (const char*)g1h + fh * 16;   // byte offset of feature half
    float2 a0 = {0.f, 0.f}, a1 = {0.f, 0.f}, a2 = {0.f, 0.f}, a3 = {0.f, 0.f};
    int beg = row_ptr[v], end = row_ptr[v + 1];
    for (int e = beg + ep; e < end; e += 4) {
        int s = csr[e];
        uint4 raw = *(const uint4*)(gbase + (size_t)s * 32);
        float2 f0 = __half22float2(*(__half2*)&raw.x);
        float2 f1 = __half22float2(*(__half2*)&raw.y);
        float2 f2 = __half22float2(*(__half2*)&raw.z);
        float2 f3 = __half22float2(*(__half2*)&raw.w);
        a0.x += f0.x; a0.y += f0.y; a1.x += f1.x; a1.y += f1.y;
        a2.x += f2.x; a2.y += f2.y; a3.x += f3.x; a3.y += f3.y;
    }
    if (ep == 0) {                              // self-loop, added once per feature
        uint4 raw = *(const uint4*)(gbase + (size_t)v * 32);
        float2 f0 = __half22float2(*(__half2*)&raw.x);
        float2 f1 = __half22float2(*(__half2*)&raw.y);
        float2 f2 = __half22float2(*(__half2*)&raw.z);
        float2 f3 = __half22float2(*(__half2*)&raw.w);
        a0.x += f0.x; a0.y += f0.y; a1.x += f1.x; a1.y += f1.y;
        a2.x += f2.x; a2.y += f2.y; a3.x += f3.x; a3.y += f3.y;
    }
    float s8[8] = {a0.x, a0.y, a1.x, a1.y, a2.x, a2.y, a3.x, a3.y};
#pragma unroll
    for (int j = 0; j < 8; ++j) {
        s8[j] += __shfl_xor(s8[j], 2, 64);
        s8[j] += __shfl_xor(s8[j], 4, 64);
    }
    float o8[8];
#pragma unroll
    for (int j = 0; j < 8; ++j) o8[j] = __shfl_xor(s8[j], 1, 64);
    float t16[16];
    if (fh == 0) {
#pragma unroll
        for (int j = 0; j < 8; ++j) { t16[j] = s8[j]; t16[8 + j] = o8[j]; }
    } else {
#pragma unroll
        for (int j = 0; j < 8; ++j) { t16[j] = o8[j]; t16[8 + j] = s8[j]; }
    }
    float d = dinv[v];
    int g = batch[v];
    int f0 = l * 4;
#pragma unroll
    for (int j = 0; j < 4; ++j) {
        float acc = 0.0f;
#pragma unroll
        for (int k = 0; k < 16; ++k) acc += t16[k] * sW[k * 32 + f0 + j];
        float h = fmaxf(d * acc + sb[f0 + j], 0.0f);
        atomicAdd(&pooled[g * 32 + f0 + j], h);
    }
    if (l == 0) atomicAdd(&cnt[g], 1.0f);
}

// ------- final linear head ---------------------------------------------------
__global__ void k_out(const float* __restrict__ pooled, const float* __restrict__ cnt,
                      const float* __restrict__ Wl, const float* __restrict__ bl,
                      float* __restrict__ out) {
    int t = blockIdx.x * blockDim.x + threadIdx.x;
    if (t >= NG * 3) return;
    int g = t / 3, c = t % 3;
    float inv = 1.0f / fmaxf(cnt[g], 1.0f);
    float s = bl[c];
#pragma unroll
    for (int f = 0; f < 32; ++f) s += pooled[g * 32 + f] * inv * Wl[f * 3 + c];
    out[g * 3 + c] = s;
}

extern "C" void kernel_launch(void* const* d_in, const int* in_sizes, int n_in,
                              void* d_out, int out_size, void* d_ws, size_t ws_size,
                              hipStream_t stream) {
    const float* x     = (const float*)d_in[0];
    const int*   ei    = (const int*)d_in[1];
    const int*   batch = (const int*)d_in[2];
    const float* W1    = (const float*)d_in[3];
    const float* b1    = (const float*)d_in[4];
    const float* W2    = (const float*)d_in[5];
    const float* b2    = (const float*)d_in[6];
    const float* Wl    = (const float*)d_in[7];
    const float* bl    = (const float*)d_in[8];

    const int N = in_sizes[0] / 3;
    const int E = in_sizes[1] / 2;
    const int* src = ei;
    const int* dst = ei + E;
    const int NBK = (N + BNODES - 1) >> BSH;      // buckets
    const int CH  = (E + NB2 - 1) / NB2;          // edges per hist/scatter block
    const int L   = NBK * NB2;                    // histogram length

    char* w = (char*)d_ws;
    int*      degi    = (int*)w;      w += (size_t)N * 4;
    int*      row_ptr = (int*)w;      w += (size_t)(N + 4) * 4;   // padded, keeps 16B align
    int*      part    = (int*)w;      w += (size_t)SCAN_B * 4;
    int*      tmp     = (int*)w;      w += (size_t)N * 4;
    float*    dinv    = (float*)w;    w += (size_t)N * 4;
    int*      histT   = (int*)w;      w += (size_t)L * 4;
    int*      tmp2    = (int*)w;      w += (size_t)L * 4;
    int*      part2   = (int*)w;      w += (size_t)SCAN_B * 4;
    int*      csr     = (int*)w;      w += (size_t)E * 4;
    // transient binned (E u32) aliases the feature buffers (xd: N float4,
    // g1h: N*16 halfs), which are written only after k_csr consumed binned.
    char*     fb      = w;
    unsigned* binned  = (unsigned*)fb;
    float4*   xd      = (float4*)fb;                            // N float4
    __half*   g1h     = (__half*)(fb + (size_t)N * 16);         // N*16 halfs
    size_t fbsz = (size_t)E * 4;
    size_t featsz = (size_t)N * 16 + (size_t)N * 32;
    w = fb + ((fbsz > featsz ? fbsz : featsz) + 15 & ~(size_t)15);
    float*    pooled  = (float*)w;    w += (size_t)NG * 32 * 4;
    float*    cnt     = (float*)w;    w += (size_t)NG * 4;

    const int B = 256;
    const int gN  = (N + B - 1) / B;
    const int gE  = (E + B - 1) / B;
    const int NBn = (N + SCAN_B - 1) / SCAN_B;    // node-scan blocks
    const int NBl = (L + SCAN_B - 1) / SCAN_B;    // hist-scan blocks

    k_zero<<<gN, B, 0, stream>>>(degi, pooled, cnt, N);
    k_deg<<<gE, B, 0, stream>>>(dst, degi, E);
    k_scanA<<<NBn, SCAN_B, 0, stream>>>(degi, tmp, part, N);
    k_scanB<<<1, SCAN_B, 0, stream>>>(part, NBn);
    k_scanC<<<gN, B, 0, stream>>>(tmp, part, row_ptr, degi, dinv, N);

    k_hist<<<NB2, B, 0, stream>>>(dst, histT, E, CH, NBK);
    k_scanA<<<NBl, SCAN_B, 0, stream>>>(histT, tmp2, part2, L);
    k_scanB<<<1, SCAN_B, 0, stream>>>(part2, NBl);
    k_applyT<<<(L + B - 1) / B, B, 0, stream>>>(tmp2, part2, histT, L);
    k_scatter<<<NB2, B, 0, stream>>>(src, dst, histT, binned, E, CH, NBK);
    k_csr<<<NBK, B, 0, stream>>>(binned, row_ptr, csr, N);

    k_xd<<<gN, B, 0, stream>>>(x, dinv, xd, N);
    k_ga<<<(N * 4 + B - 1) / B, B, 0, stream>>>(row_ptr, csr, xd, dinv, W1, b1, g1h, N);
    k_gb<<<(N * 8 + B - 1) / B, B, 0, stream>>>(row_ptr, csr, g1h, dinv, W2, b2, batch,
                                                pooled, cnt, N);
    k_out<<<(NG * 3 + B - 1) / B, B, 0, stream>>>(pooled, cnt, Wl, bl, (float*)d_out);
}

// Round 8
// 395.384 us; speedup vs baseline: 7.7288x; 1.6799x over previous
//
#include <hip/hip_runtime.h>
#include <hip/hip_fp16.h>

#define NG 1024
#define SCAN_B 1024
#define BSH 6                    // 64 nodes per bucket
#define BNODES 64
#define MAXBK 4096               // max buckets (N <= 262144)
#define NB2 256                  // histogram / scatter blocks

// ---------------- zero: pooled, cnt -----------------------------------------
__global__ void k_zero(float* __restrict__ pooled, float* __restrict__ cnt) {
    int i = blockIdx.x * blockDim.x + threadIdx.x;
    if (i < NG * 32) pooled[i] = 0.0f;
    if (i < NG) cnt[i] = 0.0f;
}

// ---------------- generic scan stage A: per-block inclusive scan ------------
__global__ void k_scanA(const int* __restrict__ in, int* __restrict__ tmp,
                        int* __restrict__ part, int L) {
    __shared__ int s[SCAN_B];
    int gid = blockIdx.x * SCAN_B + threadIdx.x;
    s[threadIdx.x] = (gid < L) ? in[gid] : 0;
    __syncthreads();
    for (int off = 1; off < SCAN_B; off <<= 1) {
        int t = (threadIdx.x >= off) ? s[threadIdx.x - off] : 0;
        __syncthreads();
        s[threadIdx.x] += t;
        __syncthreads();
    }
    if (gid < L) tmp[gid] = s[threadIdx.x];
    if (threadIdx.x == SCAN_B - 1) part[blockIdx.x] = s[SCAN_B - 1];
}

// ---------------- generic scan stage B: exclusive scan of partials ----------
__global__ void k_scanB(int* __restrict__ part, int NB) {
    __shared__ int s[SCAN_B];
    int v = (threadIdx.x < NB) ? part[threadIdx.x] : 0;
    s[threadIdx.x] = v;
    __syncthreads();
    for (int off = 1; off < SCAN_B; off <<= 1) {
        int t = (threadIdx.x >= off) ? s[threadIdx.x - off] : 0;
        __syncthreads();
        s[threadIdx.x] += t;
        __syncthreads();
    }
    if (threadIdx.x < NB) part[threadIdx.x] = threadIdx.x ? s[threadIdx.x - 1] : 0;
}

// ------- hist apply: offT = (incl + part) - orig = exclusive, in place ------
__global__ void k_applyT(const int* __restrict__ tmp2, const int* __restrict__ part2,
                         int* __restrict__ histT, int L) {
    int k = blockIdx.x * blockDim.x + threadIdx.x;
    if (k < L) histT[k] = tmp2[k] + part2[k >> 10] - histT[k];
}

// ------- pass 1: per-block bucket histogram (bucket-major output) -----------
__global__ __launch_bounds__(256) void k_hist(const int* __restrict__ dst,
                                              int* __restrict__ histT,
                                              int E, int CH, int NBK) {
    __shared__ int cnt_s[MAXBK];
    for (int i = threadIdx.x; i < NBK; i += 256) cnt_s[i] = 0;
    __syncthreads();
    int blk = blockIdx.x;
    int s0 = blk * CH, s1 = s0 + CH; if (s1 > E) s1 = E;
    for (int e = s0 + threadIdx.x; e < s1; e += 256)
        atomicAdd(&cnt_s[dst[e] >> BSH], 1);
    __syncthreads();
    for (int b = threadIdx.x; b < NBK; b += 256)
        histT[b * NB2 + blk] = cnt_s[b];
}

// ------- pass 2: scatter into per-block private windows (no global atomics) -
__global__ __launch_bounds__(256) void k_scatter(const int* __restrict__ src,
                                                 const int* __restrict__ dst,
                                                 const int* __restrict__ offT,
                                                 unsigned* __restrict__ binned,
                                                 int E, int CH, int NBK) {
    __shared__ int cur[MAXBK];
    int blk = blockIdx.x;
    for (int b = threadIdx.x; b < NBK; b += 256) cur[b] = offT[b * NB2 + blk];
    __syncthreads();
    int s0 = blk * CH, s1 = s0 + CH; if (s1 > E) s1 = E;
    for (int e = s0 + threadIdx.x; e < s1; e += 256) {
        int d = dst[e];
        int b = d >> BSH;
        int pos = atomicAdd(&cur[b], 1);       // LDS atomic, block-private
        binned[pos] = (unsigned)src[e] | ((unsigned)(d & (BNODES - 1)) << 26);
    }
}

// ------- fused: per-bucket degree count + prefix + row_ptr/dinv + CSR place -
__global__ __launch_bounds__(256) void k_csr2(
        const unsigned* __restrict__ binned, const int* __restrict__ offT,
        int* __restrict__ row_ptr, float* __restrict__ dinv,
        int* __restrict__ csr, int E, int N, int NBK) {
    __shared__ int cur[BNODES];
    __shared__ int pre[BNODES + 1];
    __shared__ int rp[BNODES];
    int t = threadIdx.x;
    int b = blockIdx.x;
    int base = offT[b << 8];                              // NB2 == 256
    int end  = (b == NBK - 1) ? E : offT[(b + 1) << 8];
    if (t < BNODES) cur[t] = 0;
    __syncthreads();
    // sweep 1: count degrees
    for (int e = base + t; e < end; e += 256)
        atomicAdd(&cur[binned[e] >> 26], 1);
    __syncthreads();
    // serial 64-entry prefix (cheap)
    if (t == 0) {
        int acc = 0;
#pragma unroll
        for (int i = 0; i < BNODES; ++i) { pre[i] = acc; acc += cur[i]; }
        pre[BNODES] = acc;
    }
    __syncthreads();
    int first = b << BSH;
    int gv = first + t;
    if (t < BNODES) {
        rp[t] = base + pre[t];
        if (gv < N) {
            row_ptr[gv] = rp[t];
            dinv[gv] = rsqrtf((float)cur[t] + 1.0f);      // +1 self-loop
        }
        cur[t] = 0;                                       // becomes cursor
    }
    if (b == NBK - 1 && t == 0) row_ptr[N] = E;
    __syncthreads();
    // sweep 2: place edges
    for (int e = base + t; e < end; e += 256) {
        unsigned ed = binned[e];
        int dl = (int)(ed >> 26);
        int pos = atomicAdd(&cur[dl], 1);
        csr[rp[dl] + pos] = (int)(ed & 0x3FFFFFFu);
    }
}

// ------- xd[v] = dinv[v] * x[v]  (padded to float4, fp32) -------------------
__global__ void k_xd(const float* __restrict__ x, const float* __restrict__ dinv,
                     float4* __restrict__ xd, int N) {
    int v = blockIdx.x * blockDim.x + threadIdx.x;
    if (v >= N) return;
    float d = dinv[v];
    xd[v] = make_float4(d * x[v * 3 + 0], d * x[v * 3 + 1], d * x[v * 3 + 2], 0.0f);
}

// ------- layer 1: gather xd (4-way edge split), matmul after aggregation ----
// writes g1h = fp16(dinv * h1); 4 lanes per node, 4 features per lane.
__global__ __launch_bounds__(256) void k_ga(const int* __restrict__ row_ptr,
                                            const int* __restrict__ csr,
                                            const float4* __restrict__ xd,
                                            const float* __restrict__ dinv,
                                            const float* __restrict__ W1,
                                            const float* __restrict__ b1,
                                            __half* __restrict__ g1h, int N) {
    __shared__ float sW[48];
    __shared__ float sb[16];
    if (threadIdx.x < 48) sW[threadIdx.x] = W1[threadIdx.x];
    if (threadIdx.x < 16) sb[threadIdx.x] = b1[threadIdx.x];
    __syncthreads();
    int t = blockIdx.x * blockDim.x + threadIdx.x;
    int v = t >> 2, l = t & 3;
    if (v >= N) return;
    int beg = row_ptr[v], end = row_ptr[v + 1];
    float sx = 0.0f, sy = 0.0f, sz = 0.0f;
    for (int e = beg + l; e < end; e += 4) {
        float4 a = xd[csr[e]];
        sx += a.x; sy += a.y; sz += a.z;
    }
    sx += __shfl_xor(sx, 1, 64); sy += __shfl_xor(sy, 1, 64); sz += __shfl_xor(sz, 1, 64);
    sx += __shfl_xor(sx, 2, 64); sy += __shfl_xor(sy, 2, 64); sz += __shfl_xor(sz, 2, 64);
    float4 self = xd[v];
    sx += self.x; sy += self.y; sz += self.z;
    float d = dinv[v];
    int f0 = l * 4;
    __half hh[4];
#pragma unroll
    for (int j = 0; j < 4; ++j) {
        int f = f0 + j;
        float h = fmaxf(d * (sx * sW[f] + sy * sW[16 + f] + sz * sW[32 + f]) + sb[f], 0.0f);
        hh[j] = __float2half(d * h);           // g1 = dinv * h1
    }
    __half2 p0 = __halves2half2(hh[0], hh[1]);
    __half2 p1 = __halves2half2(hh[2], hh[3]);
    uint2 u;
    u.x = *(unsigned*)&p0; u.y = *(unsigned*)&p1;
    *(uint2*)(g1h + (size_t)v * 16 + f0) = u;
}

// ------- layer 2: fp16 gather (4-way edge x 2-way feature split), -----------
// matmul after aggregation, fused mean-pool. 8 lanes per node.
__global__ __launch_bounds__(256) void k_gb(const int* __restrict__ row_ptr,
                                            const int* __restrict__ csr,
                                            const __half* __restrict__ g1h,
                                            const float* __restrict__ dinv,
                                            const float* __restrict__ W2,
                                            const float* __restrict__ b2,
                                            const int* __restrict__ batch,
                                            float* __restrict__ pooled,
                                            float* __restrict__ cnt, int N) {
    __shared__ float sW[512];
    __shared__ float sb[32];
    for (int i = threadIdx.x; i < 512; i += 256) sW[i] = W2[i];
    if (threadIdx.x < 32) sb[threadIdx.x] = b2[threadIdx.x];
    __syncthreads();
    int t = blockIdx.x * blockDim.x + threadIdx.x;
    int v = t >> 3, l = t & 7;
    if (v >= N) return;
    int fh = l & 1, ep = l >> 1;
    const char* gbase = (const char*)g1h + fh * 16;   // byte offset of feature half
    float2 a0 = {0.f, 0.f}, a1 = {0.f, 0.f}, a2 = {0.f, 0.f}, a3 = {0.f, 0.f};
    int beg = row_ptr[v], end = row_ptr[v + 1];
    for (int e = beg + ep; e < end; e += 4) {
        int s = csr[e];
        uint4 raw = *(const uint4*)(gbase + (size_t)s * 32);
        float2 f0 = __half22float2(*(__half2*)&raw.x);
        float2 f1 = __half22float2(*(__half2*)&raw.y);
        float2 f2 = __half22float2(*(__half2*)&raw.z);
        float2 f3 = __half22float2(*(__half2*)&raw.w);
        a0.x += f0.x; a0.y += f0.y; a1.x += f1.x; a1.y += f1.y;
        a2.x += f2.x; a2.y += f2.y; a3.x += f3.x; a3.y += f3.y;
    }
    if (ep == 0) {                              // self-loop, added once per feature
        uint4 raw = *(const uint4*)(gbase + (size_t)v * 32);
        float2 f0 = __half22float2(*(__half2*)&raw.x);
        float2 f1 = __half22float2(*(__half2*)&raw.y);
        float2 f2 = __half22float2(*(__half2*)&raw.z);
        float2 f3 = __half22float2(*(__half2*)&raw.w);
        a0.x += f0.x; a0.y += f0.y; a1.x += f1.x; a1.y += f1.y;
        a2.x += f2.x; a2.y += f2.y; a3.x += f3.x; a3.y += f3.y;
    }
    float s8[8] = {a0.x, a0.y, a1.x, a1.y, a2.x, a2.y, a3.x, a3.y};
#pragma unroll
    for (int j = 0; j < 8; ++j) {
        s8[j] += __shfl_xor(s8[j], 2, 64);
        s8[j] += __shfl_xor(s8[j], 4, 64);
    }
    float o8[8];
#pragma unroll
    for (int j = 0; j < 8; ++j) o8[j] = __shfl_xor(s8[j], 1, 64);
    float t16[16];
    if (fh == 0) {
#pragma unroll
        for (int j = 0; j < 8; ++j) { t16[j] = s8[j]; t16[8 + j] = o8[j]; }
    } else {
#pragma unroll
        for (int j = 0; j < 8; ++j) { t16[j] = o8[j]; t16[8 + j] = s8[j]; }
    }
    float d = dinv[v];
    int g = batch[v];
    int f0 = l * 4;
#pragma unroll
    for (int j = 0; j < 4; ++j) {
        float acc = 0.0f;
#pragma unroll
        for (int k = 0; k < 16; ++k) acc += t16[k] * sW[k * 32 + f0 + j];
        float h = fmaxf(d * acc + sb[f0 + j], 0.0f);
        atomicAdd(&pooled[g * 32 + f0 + j], h);
    }
    if (l == 0) atomicAdd(&cnt[g], 1.0f);
}

// ------- final linear head ---------------------------------------------------
__global__ void k_out(const float* __restrict__ pooled, const float* __restrict__ cnt,
                      const float* __restrict__ Wl, const float* __restrict__ bl,
                      float* __restrict__ out) {
    int t = blockIdx.x * blockDim.x + threadIdx.x;
    if (t >= NG * 3) return;
    int g = t / 3, c = t % 3;
    float inv = 1.0f / fmaxf(cnt[g], 1.0f);
    float s = bl[c];
#pragma unroll
    for (int f = 0; f < 32; ++f) s += pooled[g * 32 + f] * inv * Wl[f * 3 + c];
    out[g * 3 + c] = s;
}

extern "C" void kernel_launch(void* const* d_in, const int* in_sizes, int n_in,
                              void* d_out, int out_size, void* d_ws, size_t ws_size,
                              hipStream_t stream) {
    const float* x     = (const float*)d_in[0];
    const int*   ei    = (const int*)d_in[1];
    const int*   batch = (const int*)d_in[2];
    const float* W1    = (const float*)d_in[3];
    const float* b1    = (const float*)d_in[4];
    const float* W2    = (const float*)d_in[5];
    const float* b2    = (const float*)d_in[6];
    const float* Wl    = (const float*)d_in[7];
    const float* bl    = (const float*)d_in[8];

    const int N = in_sizes[0] / 3;
    const int E = in_sizes[1] / 2;
    const int* src = ei;
    const int* dst = ei + E;
    const int NBK = (N + BNODES - 1) >> BSH;      // buckets
    const int CH  = (E + NB2 - 1) / NB2;          // edges per hist/scatter block
    const int L   = NBK * NB2;                    // histogram length

    char* w = (char*)d_ws;
    int*      row_ptr = (int*)w;      w += (size_t)(N + 4) * 4;   // padded, 16B align
    float*    dinv    = (float*)w;    w += (size_t)N * 4;
    int*      histT   = (int*)w;      w += (size_t)L * 4;
    int*      tmp2    = (int*)w;      w += (size_t)L * 4;
    int*      part2   = (int*)w;      w += (size_t)SCAN_B * 4;
    int*      csr     = (int*)w;      w += (size_t)E * 4;
    // transient binned (E u32) aliases the feature buffers (xd: N float4,
    // g1h: N*16 halfs), which are written only after k_csr2 consumed binned.
    char*     fb      = w;
    unsigned* binned  = (unsigned*)fb;
    float4*   xd      = (float4*)fb;                            // N float4
    __half*   g1h     = (__half*)(fb + (size_t)N * 16);         // N*16 halfs
    size_t fbsz = (size_t)E * 4;
    size_t featsz = (size_t)N * 16 + (size_t)N * 32;
    w = fb + ((fbsz > featsz ? fbsz : featsz) + 15 & ~(size_t)15);
    float*    pooled  = (float*)w;    w += (size_t)NG * 32 * 4;
    float*    cnt     = (float*)w;    w += (size_t)NG * 4;

    const int B = 256;
    const int gN  = (N + B - 1) / B;
    const int NBl = (L + SCAN_B - 1) / SCAN_B;    // hist-scan blocks

    k_zero<<<(NG * 32 + B - 1) / B, B, 0, stream>>>(pooled, cnt);

    k_hist<<<NB2, B, 0, stream>>>(dst, histT, E, CH, NBK);
    k_scanA<<<NBl, SCAN_B, 0, stream>>>(histT, tmp2, part2, L);
    k_scanB<<<1, SCAN_B, 0, stream>>>(part2, NBl);
    k_applyT<<<(L + B - 1) / B, B, 0, stream>>>(tmp2, part2, histT, L);
    k_scatter<<<NB2, B, 0, stream>>>(src, dst, histT, binned, E, CH, NBK);
    k_csr2<<<NBK, B, 0, stream>>>(binned, histT, row_ptr, dinv, csr, E, N, NBK);

    k_xd<<<gN, B, 0, stream>>>(x, dinv, xd, N);
    k_ga<<<(N * 4 + B - 1) / B, B, 0, stream>>>(row_ptr, csr, xd, dinv, W1, b1, g1h, N);
    k_gb<<<(N * 8 + B - 1) / B, B, 0, stream>>>(row_ptr, csr, g1h, dinv, W2, b2, batch,
                                                pooled, cnt, N);
    k_out<<<(NG * 3 + B - 1) / B, B, 0, stream>>>(pooled, cnt, Wl, bl, (float*)d_out);
}

// Round 9
// 254.340 us; speedup vs baseline: 12.0148x; 1.5546x over previous
//
#include <hip/hip_runtime.h>
#include <hip/hip_fp16.h>

#define NG 1024
#define SCAN_B 1024
#define BSH 6                    // 64 nodes per bucket
#define BNODES 64
#define MAXBK 4096               // max buckets (N <= 262144)
#define NB2 256                  // histogram / scatter blocks
#define PGR 64                   // pooled LDS graph-window size

// ---------------- zero: pooled, cnt -----------------------------------------
__global__ void k_zero(float* __restrict__ pooled, float* __restrict__ cnt) {
    int i = blockIdx.x * blockDim.x + threadIdx.x;
    if (i < NG * 32) pooled[i] = 0.0f;
    if (i < NG) cnt[i] = 0.0f;
}

// ---------------- generic scan stage A: per-block inclusive scan ------------
__global__ void k_scanA(const int* __restrict__ in, int* __restrict__ tmp,
                        int* __restrict__ part, int L) {
    __shared__ int s[SCAN_B];
    int gid = blockIdx.x * SCAN_B + threadIdx.x;
    s[threadIdx.x] = (gid < L) ? in[gid] : 0;
    __syncthreads();
    for (int off = 1; off < SCAN_B; off <<= 1) {
        int t = (threadIdx.x >= off) ? s[threadIdx.x - off] : 0;
        __syncthreads();
        s[threadIdx.x] += t;
        __syncthreads();
    }
    if (gid < L) tmp[gid] = s[threadIdx.x];
    if (threadIdx.x == SCAN_B - 1) part[blockIdx.x] = s[SCAN_B - 1];
}

// ---------------- generic scan stage B: exclusive scan of partials ----------
__global__ void k_scanB(int* __restrict__ part, int NB) {
    __shared__ int s[SCAN_B];
    int v = (threadIdx.x < NB) ? part[threadIdx.x] : 0;
    s[threadIdx.x] = v;
    __syncthreads();
    for (int off = 1; off < SCAN_B; off <<= 1) {
        int t = (threadIdx.x >= off) ? s[threadIdx.x - off] : 0;
        __syncthreads();
        s[threadIdx.x] += t;
        __syncthreads();
    }
    if (threadIdx.x < NB) part[threadIdx.x] = threadIdx.x ? s[threadIdx.x - 1] : 0;
}

// ------- hist apply: offT = (incl + part) - orig = exclusive, in place ------
__global__ void k_applyT(const int* __restrict__ tmp2, const int* __restrict__ part2,
                         int* __restrict__ histT, int L) {
    int k = blockIdx.x * blockDim.x + threadIdx.x;
    if (k < L) histT[k] = tmp2[k] + part2[k >> 10] - histT[k];
}

// ------- pass 1: per-block bucket histogram (bucket-major output) -----------
__global__ __launch_bounds__(256) void k_hist(const int* __restrict__ dst,
                                              int* __restrict__ histT,
                                              int E, int CH, int NBK) {
    __shared__ int cnt_s[MAXBK];
    for (int i = threadIdx.x; i < NBK; i += 256) cnt_s[i] = 0;
    __syncthreads();
    int blk = blockIdx.x;
    int s0 = blk * CH, s1 = s0 + CH; if (s1 > E) s1 = E;
    for (int e = s0 + threadIdx.x; e < s1; e += 256)
        atomicAdd(&cnt_s[dst[e] >> BSH], 1);
    __syncthreads();
    for (int b = threadIdx.x; b < NBK; b += 256)
        histT[b * NB2 + blk] = cnt_s[b];
}

// ------- pass 2: scatter into per-block private windows (no global atomics) -
__global__ __launch_bounds__(256) void k_scatter(const int* __restrict__ src,
                                                 const int* __restrict__ dst,
                                                 const int* __restrict__ offT,
                                                 unsigned* __restrict__ binned,
                                                 int E, int CH, int NBK) {
    __shared__ int cur[MAXBK];
    int blk = blockIdx.x;
    for (int b = threadIdx.x; b < NBK; b += 256) cur[b] = offT[b * NB2 + blk];
    __syncthreads();
    int s0 = blk * CH, s1 = s0 + CH; if (s1 > E) s1 = E;
    for (int e = s0 + threadIdx.x; e < s1; e += 256) {
        int d = dst[e];
        int b = d >> BSH;
        int pos = atomicAdd(&cur[b], 1);       // LDS atomic, block-private
        binned[pos] = (unsigned)src[e] | ((unsigned)(d & (BNODES - 1)) << 26);
    }
}

// ------- fused: per-bucket degree count + prefix + row_ptr/dinv + CSR place -
__global__ __launch_bounds__(256) void k_csr2(
        const unsigned* __restrict__ binned, const int* __restrict__ offT,
        int* __restrict__ row_ptr, float* __restrict__ dinv,
        int* __restrict__ csr, int E, int N, int NBK) {
    __shared__ int cur[BNODES];
    __shared__ int pre[BNODES + 1];
    __shared__ int rp[BNODES];
    int t = threadIdx.x;
    int b = blockIdx.x;
    int base = offT[b << 8];                              // NB2 == 256
    int end  = (b == NBK - 1) ? E : offT[(b + 1) << 8];
    if (t < BNODES) cur[t] = 0;
    __syncthreads();
    for (int e = base + t; e < end; e += 256)
        atomicAdd(&cur[binned[e] >> 26], 1);
    __syncthreads();
    if (t == 0) {
        int acc = 0;
#pragma unroll
        for (int i = 0; i < BNODES; ++i) { pre[i] = acc; acc += cur[i]; }
        pre[BNODES] = acc;
    }
    __syncthreads();
    int first = b << BSH;
    int gv = first + t;
    if (t < BNODES) {
        rp[t] = base + pre[t];
        if (gv < N) {
            row_ptr[gv] = rp[t];
            dinv[gv] = rsqrtf((float)cur[t] + 1.0f);      // +1 self-loop
        }
        cur[t] = 0;                                       // becomes cursor
    }
    if (b == NBK - 1 && t == 0) row_ptr[N] = E;
    __syncthreads();
    for (int e = base + t; e < end; e += 256) {
        unsigned ed = binned[e];
        int dl = (int)(ed >> 26);
        int pos = atomicAdd(&cur[dl], 1);
        csr[rp[dl] + pos] = (int)(ed & 0x3FFFFFFu);
    }
}

// ------- xd[v] = dinv[v] * x[v]  (padded to float4, fp32) -------------------
__global__ void k_xd(const float* __restrict__ x, const float* __restrict__ dinv,
                     float4* __restrict__ xd, int N) {
    int v = blockIdx.x * blockDim.x + threadIdx.x;
    if (v >= N) return;
    float d = dinv[v];
    xd[v] = make_float4(d * x[v * 3 + 0], d * x[v * 3 + 1], d * x[v * 3 + 2], 0.0f);
}

// ------- layer 1: gather xd (8-way edge split), matmul after aggregation ----
// writes g1h = fp16(dinv * h1); 8 lanes per node, 2 features per lane.
__global__ __launch_bounds__(256) void k_ga(const int* __restrict__ row_ptr,
                                            const int* __restrict__ csr,
                                            const float4* __restrict__ xd,
                                            const float* __restrict__ dinv,
                                            const float* __restrict__ W1,
                                            const float* __restrict__ b1,
                                            __half* __restrict__ g1h, int N) {
    __shared__ float sW[48];
    __shared__ float sb[16];
    if (threadIdx.x < 48) sW[threadIdx.x] = W1[threadIdx.x];
    if (threadIdx.x < 16) sb[threadIdx.x] = b1[threadIdx.x];
    __syncthreads();
    int t = blockIdx.x * blockDim.x + threadIdx.x;
    int v = t >> 3, l = t & 7;
    if (v >= N) return;
    int beg = row_ptr[v], end = row_ptr[v + 1];
    float sx = 0.0f, sy = 0.0f, sz = 0.0f;
#pragma unroll 2
    for (int e = beg + l; e < end; e += 8) {
        float4 a = xd[csr[e]];
        sx += a.x; sy += a.y; sz += a.z;
    }
    sx += __shfl_xor(sx, 1, 64); sy += __shfl_xor(sy, 1, 64); sz += __shfl_xor(sz, 1, 64);
    sx += __shfl_xor(sx, 2, 64); sy += __shfl_xor(sy, 2, 64); sz += __shfl_xor(sz, 2, 64);
    sx += __shfl_xor(sx, 4, 64); sy += __shfl_xor(sy, 4, 64); sz += __shfl_xor(sz, 4, 64);
    float4 self = xd[v];
    sx += self.x; sy += self.y; sz += self.z;
    float d = dinv[v];
    int f0 = l * 2;
    float h0 = fmaxf(d * (sx * sW[f0]     + sy * sW[16 + f0]     + sz * sW[32 + f0])     + sb[f0],     0.0f);
    float h1 = fmaxf(d * (sx * sW[f0 + 1] + sy * sW[16 + f0 + 1] + sz * sW[32 + f0 + 1]) + sb[f0 + 1], 0.0f);
    __half2 p = __halves2half2(__float2half(d * h0), __float2half(d * h1));
    *(unsigned*)(g1h + (size_t)v * 16 + f0) = *(unsigned*)&p;
}

// ------- layer 2: fp16 gather (8-way edge x 2-way feature split), -----------
// matmul after aggregation, LDS-aggregated mean-pool. 16 lanes per node.
__global__ __launch_bounds__(256) void k_gb(const int* __restrict__ row_ptr,
                                            const int* __restrict__ csr,
                                            const __half* __restrict__ g1h,
                                            const float* __restrict__ dinv,
                                            const float* __restrict__ W2,
                                            const float* __restrict__ b2,
                                            const int* __restrict__ batch,
                                            float* __restrict__ pooled,
                                            float* __restrict__ cnt, int N) {
    __shared__ float sW[512];
    __shared__ float sb[32];
    __shared__ float sacc[PGR * 32];
    __shared__ int   scnt[PGR];
    __shared__ int   sgf;
    int t = threadIdx.x;
    for (int i = t; i < 512; i += 256) sW[i] = W2[i];
    if (t < 32) sb[t] = b2[t];
    for (int i = t; i < PGR * 32; i += 256) sacc[i] = 0.0f;
    if (t < PGR) scnt[t] = 0;
    int v0 = blockIdx.x * 16;                 // first node of this block
    if (t == 0) sgf = (v0 < N) ? batch[v0] : 0;
    __syncthreads();
    int gt = blockIdx.x * blockDim.x + t;
    int v = gt >> 4, l = gt & 15;
    int gfirst = sgf;
    if (v < N) {
        int fh = l & 1, ep = l >> 1;
        const char* gbase = (const char*)g1h + fh * 16;
        float s8[8] = {0.f, 0.f, 0.f, 0.f, 0.f, 0.f, 0.f, 0.f};
        int beg = row_ptr[v], end = row_ptr[v + 1];
#pragma unroll 2
        for (int e = beg + ep; e < end; e += 8) {
            int s = csr[e];
            uint4 raw = *(const uint4*)(gbase + (size_t)s * 32);
            float2 f0 = __half22float2(*(__half2*)&raw.x);
            float2 f1 = __half22float2(*(__half2*)&raw.y);
            float2 f2 = __half22float2(*(__half2*)&raw.z);
            float2 f3 = __half22float2(*(__half2*)&raw.w);
            s8[0] += f0.x; s8[1] += f0.y; s8[2] += f1.x; s8[3] += f1.y;
            s8[4] += f2.x; s8[5] += f2.y; s8[6] += f3.x; s8[7] += f3.y;
        }
        if (ep == 0) {                        // self-loop, once per feature half
            uint4 raw = *(const uint4*)(gbase + (size_t)v * 32);
            float2 f0 = __half22float2(*(__half2*)&raw.x);
            float2 f1 = __half22float2(*(__half2*)&raw.y);
            float2 f2 = __half22float2(*(__half2*)&raw.z);
            float2 f3 = __half22float2(*(__half2*)&raw.w);
            s8[0] += f0.x; s8[1] += f0.y; s8[2] += f1.x; s8[3] += f1.y;
            s8[4] += f2.x; s8[5] += f2.y; s8[6] += f3.x; s8[7] += f3.y;
        }
#pragma unroll
        for (int j = 0; j < 8; ++j) {
            s8[j] += __shfl_xor(s8[j], 2, 64);
            s8[j] += __shfl_xor(s8[j], 4, 64);
            s8[j] += __shfl_xor(s8[j], 8, 64);
        }
        float o8[8];
#pragma unroll
        for (int j = 0; j < 8; ++j) o8[j] = __shfl_xor(s8[j], 1, 64);
        float t16[16];
        if (fh == 0) {
#pragma unroll
            for (int j = 0; j < 8; ++j) { t16[j] = s8[j]; t16[8 + j] = o8[j]; }
        } else {
#pragma unroll
            for (int j = 0; j < 8; ++j) { t16[j] = o8[j]; t16[8 + j] = s8[j]; }
        }
        float d = dinv[v];
        int g = batch[v];
        int gl = g - gfirst;
        int f0 = l * 2;
#pragma unroll
        for (int j = 0; j < 2; ++j) {
            float acc = 0.0f;
#pragma unroll
            for (int k = 0; k < 16; ++k) acc += t16[k] * sW[k * 32 + f0 + j];
            float h = fmaxf(d * acc + sb[f0 + j], 0.0f);
            if (gl < PGR) atomicAdd(&sacc[gl * 32 + f0 + j], h);
            else          atomicAdd(&pooled[g * 32 + f0 + j], h);
        }
        if (l == 0) {
            if (gl < PGR) atomicAdd(&scnt[gl], 1);
            else          atomicAdd(&cnt[g], 1.0f);
        }
    }
    __syncthreads();
    // flush nonzero LDS slots to global
    for (int i = t; i < PGR * 32; i += 256) {
        float val = sacc[i];
        if (val != 0.0f) atomicAdd(&pooled[(gfirst + (i >> 5)) * 32 + (i & 31)], val);
    }
    for (int i = t; i < PGR; i += 256) {
        int c = scnt[i];
        if (c) atomicAdd(&cnt[gfirst + i], (float)c);
    }
}

// ------- final linear head ---------------------------------------------------
__global__ void k_out(const float* __restrict__ pooled, const float* __restrict__ cnt,
                      const float* __restrict__ Wl, const float* __restrict__ bl,
                      float* __restrict__ out) {
    int t = blockIdx.x * blockDim.x + threadIdx.x;
    if (t >= NG * 3) return;
    int g = t / 3, c = t % 3;
    float inv = 1.0f / fmaxf(cnt[g], 1.0f);
    float s = bl[c];
#pragma unroll
    for (int f = 0; f < 32; ++f) s += pooled[g * 32 + f] * inv * Wl[f * 3 + c];
    out[g * 3 + c] = s;
}

extern "C" void kernel_launch(void* const* d_in, const int* in_sizes, int n_in,
                              void* d_out, int out_size, void* d_ws, size_t ws_size,
                              hipStream_t stream) {
    const float* x     = (const float*)d_in[0];
    const int*   ei    = (const int*)d_in[1];
    const int*   batch = (const int*)d_in[2];
    const float* W1    = (const float*)d_in[3];
    const float* b1    = (const float*)d_in[4];
    const float* W2    = (const float*)d_in[5];
    const float* b2    = (const float*)d_in[6];
    const float* Wl    = (const float*)d_in[7];
    const float* bl    = (const float*)d_in[8];

    const int N = in_sizes[0] / 3;
    const int E = in_sizes[1] / 2;
    const int* src = ei;
    const int* dst = ei + E;
    const int NBK = (N + BNODES - 1) >> BSH;      // buckets
    const int CH  = (E + NB2 - 1) / NB2;          // edges per hist/scatter block
    const int L   = NBK * NB2;                    // histogram length

    char* w = (char*)d_ws;
    int*      row_ptr = (int*)w;      w += (size_t)(N + 4) * 4;   // padded, 16B align
    float*    dinv    = (float*)w;    w += (size_t)N * 4;
    int*      histT   = (int*)w;      w += (size_t)L * 4;
    int*      tmp2    = (int*)w;      w += (size_t)L * 4;
    int*      part2   = (int*)w;      w += (size_t)SCAN_B * 4;
    int*      csr     = (int*)w;      w += (size_t)E * 4;
    // transient binned (E u32) aliases the feature buffers (xd: N float4,
    // g1h: N*16 halfs), which are written only after k_csr2 consumed binned.
    char*     fb      = w;
    unsigned* binned  = (unsigned*)fb;
    float4*   xd      = (float4*)fb;                            // N float4
    __half*   g1h     = (__half*)(fb + (size_t)N * 16);         // N*16 halfs
    size_t fbsz = (size_t)E * 4;
    size_t featsz = (size_t)N * 16 + (size_t)N * 32;
    w = fb + ((fbsz > featsz ? fbsz : featsz) + 15 & ~(size_t)15);
    float*    pooled  = (float*)w;    w += (size_t)NG * 32 * 4;
    float*    cnt     = (float*)w;    w += (size_t)NG * 4;

    const int B = 256;
    const int gN  = (N + B - 1) / B;
    const int NBl = (L + SCAN_B - 1) / SCAN_B;    // hist-scan blocks

    k_zero<<<(NG * 32 + B - 1) / B, B, 0, stream>>>(pooled, cnt);

    k_hist<<<NB2, B, 0, stream>>>(dst, histT, E, CH, NBK);
    k_scanA<<<NBl, SCAN_B, 0, stream>>>(histT, tmp2, part2, L);
    k_scanB<<<1, SCAN_B, 0, stream>>>(part2, NBl);
    k_applyT<<<(L + B - 1) / B, B, 0, stream>>>(tmp2, part2, histT, L);
    k_scatter<<<NB2, B, 0, stream>>>(src, dst, histT, binned, E, CH, NBK);
    k_csr2<<<NBK, B, 0, stream>>>(binned, histT, row_ptr, dinv, csr, E, N, NBK);

    k_xd<<<gN, B, 0, stream>>>(x, dinv, xd, N);
    k_ga<<<((size_t)N * 8 + B - 1) / B, B, 0, stream>>>(row_ptr, csr, xd, dinv, W1, b1, g1h, N);
    k_gb<<<((size_t)N * 16 + B - 1) / B, B, 0, stream>>>(row_ptr, csr, g1h, dinv, W2, b2, batch,
                                                         pooled, cnt, N);
    k_out<<<(NG * 3 + B - 1) / B, B, 0, stream>>>(pooled, cnt, Wl, bl, (float*)d_out);
}

// Round 10
// 236.294 us; speedup vs baseline: 12.9324x; 1.0764x over previous
//
#include <hip/hip_runtime.h>
#include <hip/hip_fp16.h>

#define NG 1024
#define SCAN_B 1024
#define BSH 6                    // 64 nodes per bucket
#define BNODES 64
#define MAXBK 4096               // max buckets (N <= 262144)
#define NB2 128                  // histogram / scatter chunks
#define SCB 1024                 // histogram / scatter block size
#define PGR 64                   // pooled LDS graph-window size

// ---------------- zero: pooled, cnt -----------------------------------------
__global__ void k_zero(float* __restrict__ pooled, float* __restrict__ cnt) {
    int i = blockIdx.x * blockDim.x + threadIdx.x;
    if (i < NG * 32) pooled[i] = 0.0f;
    if (i < NG) cnt[i] = 0.0f;
}

// ---------------- generic scan stage A: per-block inclusive scan ------------
__global__ void k_scanA(const int* __restrict__ in, int* __restrict__ tmp,
                        int* __restrict__ part, int L) {
    __shared__ int s[SCAN_B];
    int gid = blockIdx.x * SCAN_B + threadIdx.x;
    s[threadIdx.x] = (gid < L) ? in[gid] : 0;
    __syncthreads();
    for (int off = 1; off < SCAN_B; off <<= 1) {
        int t = (threadIdx.x >= off) ? s[threadIdx.x - off] : 0;
        __syncthreads();
        s[threadIdx.x] += t;
        __syncthreads();
    }
    if (gid < L) tmp[gid] = s[threadIdx.x];
    if (threadIdx.x == SCAN_B - 1) part[blockIdx.x] = s[SCAN_B - 1];
}

// ---------------- generic scan stage B: exclusive scan of partials ----------
__global__ void k_scanB(int* __restrict__ part, int NB) {
    __shared__ int s[SCAN_B];
    int v = (threadIdx.x < NB) ? part[threadIdx.x] : 0;
    s[threadIdx.x] = v;
    __syncthreads();
    for (int off = 1; off < SCAN_B; off <<= 1) {
        int t = (threadIdx.x >= off) ? s[threadIdx.x - off] : 0;
        __syncthreads();
        s[threadIdx.x] += t;
        __syncthreads();
    }
    if (threadIdx.x < NB) part[threadIdx.x] = threadIdx.x ? s[threadIdx.x - 1] : 0;
}

// ------- hist apply: offT = (incl + part) - orig = exclusive, in place ------
__global__ void k_applyT(const int* __restrict__ tmp2, const int* __restrict__ part2,
                         int* __restrict__ histT, int L) {
    int k = blockIdx.x * blockDim.x + threadIdx.x;
    if (k < L) histT[k] = tmp2[k] + part2[k >> 10] - histT[k];
}

// ------- pass 1: per-chunk bucket histogram (bucket-major output) -----------
__global__ __launch_bounds__(SCB) void k_hist(const int* __restrict__ dst,
                                              int* __restrict__ histT,
                                              int E, int CH, int NBK) {
    __shared__ int cnt_s[MAXBK];
    for (int i = threadIdx.x; i < NBK; i += SCB) cnt_s[i] = 0;
    __syncthreads();
    int blk = blockIdx.x;
    int s0 = blk * CH, s1 = s0 + CH; if (s1 > E) s1 = E;
    for (int e = s0 + threadIdx.x; e < s1; e += SCB)
        atomicAdd(&cnt_s[dst[e] >> BSH], 1);
    __syncthreads();
    for (int b = threadIdx.x; b < NBK; b += SCB)
        histT[b * NB2 + blk] = cnt_s[b];
}

// ------- pass 2: scatter into per-chunk private windows (no global atomics) -
__global__ __launch_bounds__(SCB) void k_scatter(const int* __restrict__ src,
                                                 const int* __restrict__ dst,
                                                 const int* __restrict__ offT,
                                                 unsigned* __restrict__ binned,
                                                 int E, int CH, int NBK) {
    __shared__ int cur[MAXBK];
    int blk = blockIdx.x;
    for (int b = threadIdx.x; b < NBK; b += SCB) cur[b] = offT[b * NB2 + blk];
    __syncthreads();
    int s0 = blk * CH, s1 = s0 + CH; if (s1 > E) s1 = E;
    for (int e = s0 + threadIdx.x; e < s1; e += SCB) {
        int d = dst[e];
        int b = d >> BSH;
        int pos = atomicAdd(&cur[b], 1);       // LDS atomic, block-private
        binned[pos] = (unsigned)src[e] | ((unsigned)(d & (BNODES - 1)) << 26);
    }
}

// ------- fused: per-bucket degree count + prefix + row_ptr/dinv + CSR place -
__global__ __launch_bounds__(256) void k_csr2(
        const unsigned* __restrict__ binned, const int* __restrict__ offT,
        int* __restrict__ row_ptr, float* __restrict__ dinv,
        int* __restrict__ csr, int E, int N, int NBK) {
    __shared__ int cur[BNODES];
    __shared__ int pre[BNODES + 1];
    __shared__ int rp[BNODES];
    int t = threadIdx.x;
    int b = blockIdx.x;
    int base = offT[b * NB2];
    int end  = (b == NBK - 1) ? E : offT[(b + 1) * NB2];
    if (t < BNODES) cur[t] = 0;
    __syncthreads();
    for (int e = base + t; e < end; e += 256)
        atomicAdd(&cur[binned[e] >> 26], 1);
    __syncthreads();
    if (t == 0) {
        int acc = 0;
#pragma unroll
        for (int i = 0; i < BNODES; ++i) { pre[i] = acc; acc += cur[i]; }
        pre[BNODES] = acc;
    }
    __syncthreads();
    int first = b << BSH;
    int gv = first + t;
    if (t < BNODES) {
        rp[t] = base + pre[t];
        if (gv < N) {
            row_ptr[gv] = rp[t];
            dinv[gv] = rsqrtf((float)cur[t] + 1.0f);      // +1 self-loop
        }
        cur[t] = 0;                                       // becomes cursor
    }
    if (b == NBK - 1 && t == 0) row_ptr[N] = E;
    __syncthreads();
    for (int e = base + t; e < end; e += 256) {
        unsigned ed = binned[e];
        int dl = (int)(ed >> 26);
        int pos = atomicAdd(&cur[dl], 1);
        csr[rp[dl] + pos] = (int)(ed & 0x3FFFFFFu);
    }
}

// ------- xd[v] = dinv[v] * x[v]  (padded to float4, fp32) -------------------
__global__ void k_xd(const float* __restrict__ x, const float* __restrict__ dinv,
                     float4* __restrict__ xd, int N) {
    int v = blockIdx.x * blockDim.x + threadIdx.x;
    if (v >= N) return;
    float d = dinv[v];
    xd[v] = make_float4(d * x[v * 3 + 0], d * x[v * 3 + 1], d * x[v * 3 + 2], 0.0f);
}

// ------- layer 1: gather xd (8-way edge split), matmul after aggregation ----
// writes g1h = fp16(dinv * h1); 8 lanes per node, 2 features per lane.
__global__ __launch_bounds__(256) void k_ga(const int* __restrict__ row_ptr,
                                            const int* __restrict__ csr,
                                            const float4* __restrict__ xd,
                                            const float* __restrict__ dinv,
                                            const float* __restrict__ W1,
                                            const float* __restrict__ b1,
                                            __half* __restrict__ g1h, int N) {
    __shared__ float sW[48];
    __shared__ float sb[16];
    if (threadIdx.x < 48) sW[threadIdx.x] = W1[threadIdx.x];
    if (threadIdx.x < 16) sb[threadIdx.x] = b1[threadIdx.x];
    __syncthreads();
    int t = blockIdx.x * blockDim.x + threadIdx.x;
    int v = t >> 3, l = t & 7;
    if (v >= N) return;
    int beg = row_ptr[v], end = row_ptr[v + 1];
    float sx = 0.0f, sy = 0.0f, sz = 0.0f;
#pragma unroll 2
    for (int e = beg + l; e < end; e += 8) {
        float4 a = xd[csr[e]];
        sx += a.x; sy += a.y; sz += a.z;
    }
    sx += __shfl_xor(sx, 1, 64); sy += __shfl_xor(sy, 1, 64); sz += __shfl_xor(sz, 1, 64);
    sx += __shfl_xor(sx, 2, 64); sy += __shfl_xor(sy, 2, 64); sz += __shfl_xor(sz, 2, 64);
    sx += __shfl_xor(sx, 4, 64); sy += __shfl_xor(sy, 4, 64); sz += __shfl_xor(sz, 4, 64);
    float4 self = xd[v];
    sx += self.x; sy += self.y; sz += self.z;
    float d = dinv[v];
    int f0 = l * 2;
    float h0 = fmaxf(d * (sx * sW[f0]     + sy * sW[16 + f0]     + sz * sW[32 + f0])     + sb[f0],     0.0f);
    float h1 = fmaxf(d * (sx * sW[f0 + 1] + sy * sW[16 + f0 + 1] + sz * sW[32 + f0 + 1]) + sb[f0 + 1], 0.0f);
    __half2 p = __halves2half2(__float2half(d * h0), __float2half(d * h1));
    *(unsigned*)(g1h + (size_t)v * 16 + f0) = *(unsigned*)&p;
}

// ------- layer 2: fp16 gather (8-way edge x 2-way feature split), -----------
// matmul after aggregation, LDS-aggregated mean-pool. 16 lanes per node.
__global__ __launch_bounds__(256) void k_gb(const int* __restrict__ row_ptr,
                                            const int* __restrict__ csr,
                                            const __half* __restrict__ g1h,
                                            const float* __restrict__ dinv,
                                            const float* __restrict__ W2,
                                            const float* __restrict__ b2,
                                            const int* __restrict__ batch,
                                            float* __restrict__ pooled,
                                            float* __restrict__ cnt, int N) {
    __shared__ float sW[512];
    __shared__ float sb[32];
    __shared__ float sacc[PGR * 32];
    __shared__ int   scnt[PGR];
    __shared__ int   sgf;
    int t = threadIdx.x;
    for (int i = t; i < 512; i += 256) sW[i] = W2[i];
    if (t < 32) sb[t] = b2[t];
    for (int i = t; i < PGR * 32; i += 256) sacc[i] = 0.0f;
    if (t < PGR) scnt[t] = 0;
    int v0 = blockIdx.x * 16;                 // first node of this block
    if (t == 0) sgf = (v0 < N) ? batch[v0] : 0;
    __syncthreads();
    int gt = blockIdx.x * blockDim.x + t;
    int v = gt >> 4, l = gt & 15;
    int gfirst = sgf;
    if (v < N) {
        int fh = l & 1, ep = l >> 1;
        const char* gbase = (const char*)g1h + fh * 16;
        float s8[8] = {0.f, 0.f, 0.f, 0.f, 0.f, 0.f, 0.f, 0.f};
        int beg = row_ptr[v], end = row_ptr[v + 1];
#pragma unroll 2
        for (int e = beg + ep; e < end; e += 8) {
            int s = csr[e];
            uint4 raw = *(const uint4*)(gbase + (size_t)s * 32);
            float2 f0 = __half22float2(*(__half2*)&raw.x);
            float2 f1 = __half22float2(*(__half2*)&raw.y);
            float2 f2 = __half22float2(*(__half2*)&raw.z);
            float2 f3 = __half22float2(*(__half2*)&raw.w);
            s8[0] += f0.x; s8[1] += f0.y; s8[2] += f1.x; s8[3] += f1.y;
            s8[4] += f2.x; s8[5] += f2.y; s8[6] += f3.x; s8[7] += f3.y;
        }
        if (ep == 0) {                        // self-loop, once per feature half
            uint4 raw = *(const uint4*)(gbase + (size_t)v * 32);
            float2 f0 = __half22float2(*(__half2*)&raw.x);
            float2 f1 = __half22float2(*(__half2*)&raw.y);
            float2 f2 = __half22float2(*(__half2*)&raw.z);
            float2 f3 = __half22float2(*(__half2*)&raw.w);
            s8[0] += f0.x; s8[1] += f0.y; s8[2] += f1.x; s8[3] += f1.y;
            s8[4] += f2.x; s8[5] += f2.y; s8[6] += f3.x; s8[7] += f3.y;
        }
#pragma unroll
        for (int j = 0; j < 8; ++j) {
            s8[j] += __shfl_xor(s8[j], 2, 64);
            s8[j] += __shfl_xor(s8[j], 4, 64);
            s8[j] += __shfl_xor(s8[j], 8, 64);
        }
        float o8[8];
#pragma unroll
        for (int j = 0; j < 8; ++j) o8[j] = __shfl_xor(s8[j], 1, 64);
        float t16[16];
        if (fh == 0) {
#pragma unroll
            for (int j = 0; j < 8; ++j) { t16[j] = s8[j]; t16[8 + j] = o8[j]; }
        } else {
#pragma unroll
            for (int j = 0; j < 8; ++j) { t16[j] = o8[j]; t16[8 + j] = s8[j]; }
        }
        float d = dinv[v];
        int g = batch[v];
        int gl = g - gfirst;
        int f0 = l * 2;
#pragma unroll
        for (int j = 0; j < 2; ++j) {
            float acc = 0.0f;
#pragma unroll
            for (int k = 0; k < 16; ++k) acc += t16[k] * sW[k * 32 + f0 + j];
            float h = fmaxf(d * acc + sb[f0 + j], 0.0f);
            if (gl < PGR) atomicAdd(&sacc[gl * 32 + f0 + j], h);
            else          atomicAdd(&pooled[g * 32 + f0 + j], h);
        }
        if (l == 0) {
            if (gl < PGR) atomicAdd(&scnt[gl], 1);
            else          atomicAdd(&cnt[g], 1.0f);
        }
    }
    __syncthreads();
    // flush nonzero LDS slots to global
    for (int i = t; i < PGR * 32; i += 256) {
        float val = sacc[i];
        if (val != 0.0f) atomicAdd(&pooled[(gfirst + (i >> 5)) * 32 + (i & 31)], val);
    }
    for (int i = t; i < PGR; i += 256) {
        int c = scnt[i];
        if (c) atomicAdd(&cnt[gfirst + i], (float)c);
    }
}

// ------- final linear head ---------------------------------------------------
__global__ void k_out(const float* __restrict__ pooled, const float* __restrict__ cnt,
                      const float* __restrict__ Wl, const float* __restrict__ bl,
                      float* __restrict__ out) {
    int t = blockIdx.x * blockDim.x + threadIdx.x;
    if (t >= NG * 3) return;
    int g = t / 3, c = t % 3;
    float inv = 1.0f / fmaxf(cnt[g], 1.0f);
    float s = bl[c];
#pragma unroll
    for (int f = 0; f < 32; ++f) s += pooled[g * 32 + f] * inv * Wl[f * 3 + c];
    out[g * 3 + c] = s;
}

extern "C" void kernel_launch(void* const* d_in, const int* in_sizes, int n_in,
                              void* d_out, int out_size, void* d_ws, size_t ws_size,
                              hipStream_t stream) {
    const float* x     = (const float*)d_in[0];
    const int*   ei    = (const int*)d_in[1];
    const int*   batch = (const int*)d_in[2];
    const float* W1    = (const float*)d_in[3];
    const float* b1    = (const float*)d_in[4];
    const float* W2    = (const float*)d_in[5];
    const float* b2    = (const float*)d_in[6];
    const float* Wl    = (const float*)d_in[7];
    const float* bl    = (const float*)d_in[8];

    const int N = in_sizes[0] / 3;
    const int E = in_sizes[1] / 2;
    const int* src = ei;
    const int* dst = ei + E;
    const int NBK = (N + BNODES - 1) >> BSH;      // buckets
    const int CH  = (E + NB2 - 1) / NB2;          // edges per hist/scatter chunk
    const int L   = NBK * NB2;                    // histogram length

    char* w = (char*)d_ws;
    int*      row_ptr = (int*)w;      w += (size_t)(N + 4) * 4;   // padded, 16B align
    float*    dinv    = (float*)w;    w += (size_t)N * 4;
    int*      histT   = (int*)w;      w += (size_t)L * 4;
    int*      tmp2    = (int*)w;      w += (size_t)L * 4;
    int*      part2   = (int*)w;      w += (size_t)SCAN_B * 4;
    int*      csr     = (int*)w;      w += (size_t)E * 4;
    // transient binned (E u32) aliases the feature buffers (xd: N float4,
    // g1h: N*16 halfs), which are written only after k_csr2 consumed binned.
    char*     fb      = w;
    unsigned* binned  = (unsigned*)fb;
    float4*   xd      = (float4*)fb;                            // N float4
    __half*   g1h     = (__half*)(fb + (size_t)N * 16);         // N*16 halfs
    size_t fbsz = (size_t)E * 4;
    size_t featsz = (size_t)N * 16 + (size_t)N * 32;
    w = fb + ((fbsz > featsz ? fbsz : featsz) + 15 & ~(size_t)15);
    float*    pooled  = (float*)w;    w += (size_t)NG * 32 * 4;
    float*    cnt     = (float*)w;    w += (size_t)NG * 4;

    const int B = 256;
    const int gN  = (N + B - 1) / B;
    const int NBl = (L + SCAN_B - 1) / SCAN_B;    // hist-scan blocks

    k_zero<<<(NG * 32 + B - 1) / B, B, 0, stream>>>(pooled, cnt);

    k_hist<<<NB2, SCB, 0, stream>>>(dst, histT, E, CH, NBK);
    k_scanA<<<NBl, SCAN_B, 0, stream>>>(histT, tmp2, part2, L);
    k_scanB<<<1, SCAN_B, 0, stream>>>(part2, NBl);
    k_applyT<<<(L + B - 1) / B, B, 0, stream>>>(tmp2, part2, histT, L);
    k_scatter<<<NB2, SCB, 0, stream>>>(src, dst, histT, binned, E, CH, NBK);
    k_csr2<<<NBK, B, 0, stream>>>(binned, histT, row_ptr, dinv, csr, E, N, NBK);

    k_xd<<<gN, B, 0, stream>>>(x, dinv, xd, N);
    k_ga<<<((size_t)N * 8 + B - 1) / B, B, 0, stream>>>(row_ptr, csr, xd, dinv, W1, b1, g1h, N);
    k_gb<<<((size_t)N * 16 + B - 1) / B, B, 0, stream>>>(row_ptr, csr, g1h, dinv, W2, b2, batch,
                                                         pooled, cnt, N);
    k_out<<<(NG * 3 + B - 1) / B, B, 0, stream>>>(pooled, cnt, Wl, bl, (float*)d_out);
}